// Round 13
// baseline (483.953 us; speedup 1.0000x reference)
//
#include <hip/hip_runtime.h>

#define B 8
#define N 1024
#define M 128
#define KF 16
#define C 16
#define DPE 64
#define NE 131072
#define NV (B*N)
#define NM (N*M)
#define BN_EPS 1e-5f

typedef short bf16x8 __attribute__((ext_vector_type(8)));
typedef float f32x4 __attribute__((ext_vector_type(4)));

__device__ inline unsigned short f2bf_rne(float f) {
    unsigned u = __float_as_uint(f);
    u += 0x7fffu + ((u >> 16) & 1u);
    return (unsigned short)(u >> 16);
}
__device__ inline void split_bf16(float v, unsigned short& hi, unsigned short& lo) {
    hi = f2bf_rne(v);
    float hf = __uint_as_float((unsigned)hi << 16);
    lo = f2bf_rne(v - hf);
}
union U4 { uint4 v; unsigned short s[8]; };

// Sf frag-major (uint4 units): SF4(b,nsub,ks,hl,l) ; el = S[n=16nsub+(l&15)][k=32ks+8(l>>4)+j]
__device__ __host__ inline size_t SF4(int b, int nsub, int ks, int hl, int l) {
    return ((((size_t)b * 64 + nsub) * 32 + ks) * 2 + hl) * 64 + l;
}
// Pf frag-major (uint4 units) per buffer: PF4(b,msub,ks,hl,l)
__device__ __host__ inline size_t PF4(int b, int msub, int ks, int hl, int l) {
    return ((((size_t)b * 8 + msub) * 32 + ks) * 2 + hl) * 64 + l;
}
#define PFBUF ((size_t)B * 8 * 32 * 2 * 64)   // uint4 per Pf buffer (4MB)

// ---------- prep: S -> frag-major hi/lo bf16 (XCD-aligned: b = blk&7) ----------
__global__ __launch_bounds__(256) void prep_s(const float* __restrict__ Lap, uint4* __restrict__ Sf) {
    int b = blockIdx.x & 7, nb = blockIdx.x >> 3;
    int t = threadIdx.x;
    int nl = t >> 4, kg = t & 15;
    int n = nb * 16 + nl;
    const float* row = Lap + ((size_t)b * N + n) * N;
    #pragma unroll
    for (int jj = 0; jj < 8; jj++) {
        int koct = kg + 16 * jj;
        int k0 = koct * 8;
        float4 f0 = *(const float4*)(row + k0);
        float4 f1 = *(const float4*)(row + k0 + 4);
        float e[8] = {f0.x, f0.y, f0.z, f0.w, f1.x, f1.y, f1.z, f1.w};
        U4 hi, lo;
        #pragma unroll
        for (int j = 0; j < 8; j++) split_bf16(e[j], hi.s[j], lo.s[j]);
        int ks = k0 >> 5;
        int lf = nl + 16 * (koct & 3);
        Sf[SF4(b, nb, ks, 0, lf)] = hi.v;
        Sf[SF4(b, nb, ks, 1, lf)] = lo.v;
    }
}

// ---------- prep: W -> feat plane0 (W^T, [m][node]) (XCD-aligned) ----------
__global__ __launch_bounds__(256) void prep_w_plane(const float* __restrict__ W, float* __restrict__ feat) {
    __shared__ float T[32][33];
    int b = blockIdx.x & 7;
    int tile = blockIdx.x >> 3;
    int nt = tile & 31, mt = tile >> 5;
    int n0 = nt * 32, m0 = mt * 32;
    int t = threadIdx.x;
    {
        int nl = t >> 3, mq = t & 7;
        float4 v = *(const float4*)(W + ((size_t)b * N + n0 + nl) * M + m0 + mq * 4);
        T[nl][mq * 4 + 0] = v.x; T[nl][mq * 4 + 1] = v.y;
        T[nl][mq * 4 + 2] = v.z; T[nl][mq * 4 + 3] = v.w;
    }
    __syncthreads();
    {
        int ml = t >> 3, nq = t & 7;
        float4 v = make_float4(T[nq * 4 + 0][ml], T[nq * 4 + 1][ml], T[nq * 4 + 2][ml], T[nq * 4 + 3][ml]);
        float* plane = feat + (size_t)b * KF * NM;
        *(float4*)(plane + (size_t)(m0 + ml) * N + n0 + nq * 4) = v;
    }
}

// ---------- prep: W -> Pf buffer 0 (XCD-aligned) ----------
__global__ __launch_bounds__(256) void prep_w_frag(const float* __restrict__ W, uint4* __restrict__ Pf) {
    int b = blockIdx.x & 7;
    int r = (blockIdx.x >> 3) * 256 + threadIdx.x;
    int msub = r >> 11, ks = (r >> 6) & 31, l = r & 63;
    int m = 16 * msub + (l & 15);
    U4 hi, lo;
    #pragma unroll
    for (int j = 0; j < 8; j++) {
        int n = 32 * ks + 8 * (l >> 4) + j;
        float v = W[((size_t)b * N + n) * M + m];
        split_bf16(v, hi.s[j], lo.s[j]);
    }
    Pf[PF4(b, msub, ks, 0, l)] = hi.v;
    Pf[PF4(b, msub, ks, 1, l)] = lo.v;
}

// ---------- persistent MFMA chain: 15 steps of D = P^T @ S (bf16x3) ----------
// 256 blocks x 512 thr (R5-proven co-resident). b=blk&7 pins batch b to XCD b
// (R8-measured round-robin), so Pf producer+consumer share ONE L2: no
// cross-XCD coherence needed. Per-step sync = per-batch relaxed-atomic spin
// barrier (NO __threadfence -> no L2 flush, the R5 killer) + `buffer_inv sc0`
// (L1-only invalidate) per wave before consuming the new Pf.
__global__ __launch_bounds__(512) void gemm_chain(const uint4* __restrict__ Sf,
                                                  uint4* __restrict__ PfA,
                                                  uint4* __restrict__ PfB,
                                                  float* __restrict__ feat,
                                                  unsigned* bar) {
    __shared__ __align__(16) char smem[32768];
    uint4* ldsB = (uint4*)smem;               // [g][p][512] uint4 = 32 KB
    float* Dl = (float*)smem;                 // 128 x 36 floats (epilogue alias)
    f32x4* accbuf = (f32x4*)smem;             // epilogue alias

    int b = blockIdx.x & 7, bx = blockIdx.x >> 3;   // XCD pinning
    int t = threadIdx.x;
    int w = t >> 6, lane = t & 63;
    int g = w >> 2, wp = w & 3;
    int u = t & 255;
    size_t sbase = SF4(b, 2 * bx, 0, 0, 0);
    int n0 = 32 * bx;

    #pragma unroll 1
    for (int k = 0; k < KF - 1; k++) {
        const uint4* PfIn = (k & 1) ? PfB : PfA;
        uint4* PfOut      = (k & 1) ? PfA : PfB;

        f32x4 acc[2][2] = {};
        uint4 areg[2][2][2][2];               // [ping][ksl][mi][hl]
        uint4 breg[2][2];

        breg[0][0] = Sf[sbase + u + 256 * (8 * g)];
        breg[0][1] = Sf[sbase + 4096 + u + 256 * (8 * g)];
        #pragma unroll
        for (int ksl = 0; ksl < 2; ksl++)
            #pragma unroll
            for (int mi = 0; mi < 2; mi++) {
                areg[0][ksl][mi][0] = PfIn[PF4(b, 2 * wp + mi, 16 * g + ksl, 0, lane)];
                areg[0][ksl][mi][1] = PfIn[PF4(b, 2 * wp + mi, 16 * g + ksl, 1, lane)];
            }

        #pragma unroll 2
        for (int it = 0; it < 8; it++) {
            int p = it & 1;
            int ck = 8 * g + it;
            if (it < 7) {
                #pragma unroll
                for (int ksl = 0; ksl < 2; ksl++)
                    #pragma unroll
                    for (int mi = 0; mi < 2; mi++) {
                        areg[p ^ 1][ksl][mi][0] = PfIn[PF4(b, 2 * wp + mi, 2 * (ck + 1) + ksl, 0, lane)];
                        areg[p ^ 1][ksl][mi][1] = PfIn[PF4(b, 2 * wp + mi, 2 * (ck + 1) + ksl, 1, lane)];
                    }
            }
            ldsB[g * 1024 + p * 512 + u] = breg[p][0];
            ldsB[g * 1024 + p * 512 + u + 256] = breg[p][1];
            if (it < 7) {
                breg[p ^ 1][0] = Sf[sbase + u + 256 * (size_t)(ck + 1)];
                breg[p ^ 1][1] = Sf[sbase + 4096 + u + 256 * (size_t)(ck + 1)];
            }
            __syncthreads();
            #pragma unroll
            for (int ksl = 0; ksl < 2; ksl++) {
                bf16x8 bh[2], bl[2];
                #pragma unroll
                for (int ni = 0; ni < 2; ni++) {
                    bh[ni] = __builtin_bit_cast(bf16x8, ldsB[g * 1024 + p * 512 + ni * 256 + ksl * 128 + lane]);
                    bl[ni] = __builtin_bit_cast(bf16x8, ldsB[g * 1024 + p * 512 + ni * 256 + ksl * 128 + 64 + lane]);
                }
                #pragma unroll
                for (int mi = 0; mi < 2; mi++) {
                    bf16x8 ah = __builtin_bit_cast(bf16x8, areg[p][ksl][mi][0]);
                    bf16x8 al = __builtin_bit_cast(bf16x8, areg[p][ksl][mi][1]);
                    #pragma unroll
                    for (int ni = 0; ni < 2; ni++) {
                        acc[mi][ni] = __builtin_amdgcn_mfma_f32_16x16x32_bf16(ah, bh[ni], acc[mi][ni], 0, 0, 0);
                        acc[mi][ni] = __builtin_amdgcn_mfma_f32_16x16x32_bf16(ah, bl[ni], acc[mi][ni], 0, 0, 0);
                        acc[mi][ni] = __builtin_amdgcn_mfma_f32_16x16x32_bf16(al, bh[ni], acc[mi][ni], 0, 0, 0);
                    }
                }
            }
        }

        // ---- epilogue: cross-group K-reduction, then plane + frag writes ----
        __syncthreads();
        if (g == 1) {
            #pragma unroll
            for (int mi = 0; mi < 2; mi++)
                #pragma unroll
                for (int ni = 0; ni < 2; ni++)
                    accbuf[((wp * 2 + mi) * 2 + ni) * 64 + lane] = acc[mi][ni];
        }
        __syncthreads();
        if (g == 0) {
            #pragma unroll
            for (int mi = 0; mi < 2; mi++)
                #pragma unroll
                for (int ni = 0; ni < 2; ni++)
                    acc[mi][ni] += accbuf[((wp * 2 + mi) * 2 + ni) * 64 + lane];
        }
        __syncthreads();
        if (g == 0) {
            #pragma unroll
            for (int mi = 0; mi < 2; mi++)
                #pragma unroll
                for (int ni = 0; ni < 2; ni++)
                    #pragma unroll
                    for (int r = 0; r < 4; r++) {
                        int m = 32 * wp + 16 * mi + 4 * (lane >> 4) + r;
                        int n = 16 * ni + (lane & 15);
                        Dl[m * 36 + n] = acc[mi][ni][r];
                    }
        }
        __syncthreads();
        {   // f32 plane write ([m][node]); 512 threads x 8 floats
            int m = t >> 2, c0 = (t & 3) * 8;
            float* plane = feat + ((size_t)b * KF + (k + 1)) * NM + (size_t)m * N + n0 + c0;
            ((float4*)plane)[0] = *(const float4*)&Dl[m * 36 + c0];
            ((float4*)plane)[1] = *(const float4*)&Dl[m * 36 + c0 + 4];
        }
        if (k < KF - 2) {
            {   // next-step A frags (hi/lo), ks = bx
                int msub = t >> 6, l = t & 63;
                int m = 16 * msub + (l & 15);
                int ncol = 8 * (l >> 4);
                float4 v0 = *(const float4*)&Dl[m * 36 + ncol];
                float4 v1 = *(const float4*)&Dl[m * 36 + ncol + 4];
                float e[8] = {v0.x, v0.y, v0.z, v0.w, v1.x, v1.y, v1.z, v1.w};
                U4 hi, lo;
                #pragma unroll
                for (int j = 0; j < 8; j++) split_bf16(e[j], hi.s[j], lo.s[j]);
                PfOut[PF4(b, msub, bx, 0, l)] = hi.v;
                PfOut[PF4(b, msub, bx, 1, l)] = lo.v;
            }
            // ---- per-batch (same-XCD) barrier: no fences, no L2 flush ----
            __syncthreads();   // drains all waves' Pf stores to L2 (vmcnt(0))
            if (t == 0) {
                __hip_atomic_fetch_add(&bar[b * 32], 1u, __ATOMIC_RELAXED,
                                       __HIP_MEMORY_SCOPE_AGENT);
                unsigned target = 32u * (unsigned)(k + 1);
                while (__hip_atomic_load(&bar[b * 32], __ATOMIC_RELAXED,
                                         __HIP_MEMORY_SCOPE_AGENT) < target)
                    __builtin_amdgcn_s_sleep(1);
            }
            __syncthreads();
            // invalidate this CU's vector L1 so Pf reads come from (fresh) L2
            asm volatile("buffer_inv sc0\n\ts_waitcnt vmcnt(0)" ::: "memory");
        }
    }
}

// ---------- BN stats (XCD-aligned) ----------
__global__ __launch_bounds__(256) void bn_stats(const float* __restrict__ feat,
                                                const float* __restrict__ lin_w,
                                                const float* __restrict__ lin_b,
                                                float* __restrict__ stats) {
    __shared__ float wls[KF * C];
    __shared__ float red[4][2][C];
    int t = threadIdx.x;
    wls[t] = lin_w[t];
    __syncthreads();
    int b = blockIdx.x & 7;
    int i = (blockIdx.x >> 3) * 256 + t;
    const float4* fb = (const float4*)(feat + (size_t)b * KF * NM);

    float4 hacc[C];
    #pragma unroll
    for (int c = 0; c < C; c++) {
        float bb = lin_b[c];
        hacc[c] = make_float4(bb, bb, bb, bb);
    }
    for (int kk = 0; kk < KF; kk++) {
        float4 pv = fb[(size_t)kk * (NM / 4) + i];
        #pragma unroll
        for (int c = 0; c < C; c++) {
            float wv = wls[kk * C + c];
            hacc[c].x = fmaf(pv.x, wv, hacc[c].x);
            hacc[c].y = fmaf(pv.y, wv, hacc[c].y);
            hacc[c].z = fmaf(pv.z, wv, hacc[c].z);
            hacc[c].w = fmaf(pv.w, wv, hacc[c].w);
        }
    }
    float s[C], ss[C];
    #pragma unroll
    for (int c = 0; c < C; c++) {
        float4 h = hacc[c];
        s[c] = h.x + h.y + h.z + h.w;
        ss[c] = h.x * h.x + h.y * h.y + h.z * h.z + h.w * h.w;
    }
    #pragma unroll
    for (int off = 32; off > 0; off >>= 1)
        #pragma unroll
        for (int c = 0; c < C; c++) {
            s[c] += __shfl_down(s[c], off);
            ss[c] += __shfl_down(ss[c], off);
        }
    if ((t & 63) == 0) {
        int wv = t >> 6;
        #pragma unroll
        for (int c = 0; c < C; c++) { red[wv][0][c] = s[c]; red[wv][1][c] = ss[c]; }
    }
    __syncthreads();
    if (t < 32) {
        int which = t >> 4, c = t & 15;
        float v = red[0][which][c] + red[1][which][c] + red[2][which][c] + red[3][which][c];
        atomicAdd(&stats[b * 32 + which * 16 + c], v);
    }
}

// ---------- BN apply + relu + mean over M -> x ----------
__global__ __launch_bounds__(256) void bn_x(const float* __restrict__ feat,
                                            const float* __restrict__ lin_w,
                                            const float* __restrict__ lin_b,
                                            const float* __restrict__ gam,
                                            const float* __restrict__ bet,
                                            const float* __restrict__ stats,
                                            float* __restrict__ x) {
    __shared__ float wls[KF * C];
    __shared__ float red[8][32 * 17];
    int t = threadIdx.x;
    wls[t] = lin_w[t];
    __syncthreads();
    int grp = blockIdx.x;
    int b = grp & 7, n0 = (grp >> 3) * 32;
    int nl = t & 31, mg = t >> 5;
    int n = n0 + nl;

    const float inv_nm = 1.0f / (float)NM;
    float sc[C], sh[C], bb[C];
    #pragma unroll
    for (int c = 0; c < C; c++) {
        float mean = stats[b * 32 + c] * inv_nm;
        float var = stats[b * 32 + 16 + c] * inv_nm - mean * mean;
        sc[c] = gam[c] * rsqrtf(var + BN_EPS);
        sh[c] = bet[c] - mean * sc[c];
        bb[c] = lin_b[c];
    }
    const float* fb = feat + (size_t)b * KF * NM + n;
    float y[C] = {};
    for (int m = mg * 16; m < mg * 16 + 16; m++) {
        float p[KF];
        #pragma unroll
        for (int kk = 0; kk < KF; kk++) p[kk] = fb[(size_t)kk * NM + (size_t)m * N];
        #pragma unroll
        for (int c = 0; c < C; c++) {
            float h = bb[c];
            #pragma unroll
            for (int kk = 0; kk < KF; kk++) h = fmaf(p[kk], wls[kk * C + c], h);
            y[c] += fmaxf(fmaf(h, sc[c], sh[c]), 0.0f);
        }
    }
    #pragma unroll
    for (int c = 0; c < C; c++) red[mg][nl * 17 + c] = y[c];
    __syncthreads();
    #pragma unroll
    for (int q = 0; q < 2; q++) {
        int slot = t + q * 256;
        int snl = slot >> 4, c = slot & 15;
        float v = 0.0f;
        #pragma unroll
        for (int m8 = 0; m8 < 8; m8++) v += red[m8][snl * 17 + c];
        v *= (1.0f / (float)M);
        x[((size_t)b * N + n0 + snl) * C + c] = v;
    }
}

// ---------- edge CSR build + gather ----------
__global__ __launch_bounds__(256) void edge_hist(const int* __restrict__ ei, int* __restrict__ cnt) {
    int e = blockIdx.x * 256 + threadIdx.x;
    bool is64 = (ei[1] == 0 && ei[3] == 0 && ei[5] == 0 && ei[7] == 0);
    int dst = is64 ? ei[2 * (NE + e)] : ei[NE + e];
    atomicAdd(&cnt[dst], 1);
}

__global__ __launch_bounds__(256) void edge_scan(const int* __restrict__ cnt,
                                                 int* __restrict__ off, int* __restrict__ cur) {
    __shared__ int ss[256];
    int t = threadIdx.x;
    int base = t * 32;
    int local[32];
    int s = 0;
    #pragma unroll
    for (int i = 0; i < 32; i++) { local[i] = cnt[base + i]; s += local[i]; }
    ss[t] = s;
    __syncthreads();
    #pragma unroll
    for (int d = 1; d < 256; d <<= 1) {
        int v = (t >= d) ? ss[t - d] : 0;
        __syncthreads();
        ss[t] += v;
        __syncthreads();
    }
    int excl = ss[t] - s;
    #pragma unroll
    for (int i = 0; i < 32; i++) { off[base + i] = excl; cur[base + i] = excl; excl += local[i]; }
}

__global__ __launch_bounds__(256) void edge_fill(const int* __restrict__ ei,
                                                 int* __restrict__ cur, int* __restrict__ bucket) {
    int e = blockIdx.x * 256 + threadIdx.x;
    bool is64 = (ei[1] == 0 && ei[3] == 0 && ei[5] == 0 && ei[7] == 0);
    int src, dst;
    if (is64) { src = ei[2 * e]; dst = ei[2 * (NE + e)]; }
    else      { src = ei[e];     dst = ei[NE + e]; }
    int pos = atomicAdd(&cur[dst], 1);
    bucket[pos] = src;
}

__global__ __launch_bounds__(256) void edge_gather(const int* __restrict__ cnt,
                                                   const int* __restrict__ off,
                                                   const int* __restrict__ bucket,
                                                   const float* __restrict__ x,
                                                   float* __restrict__ g) {
    int t = threadIdx.x;
    int grp = t >> 4, c = t & 15;
    int n = blockIdx.x * 16 + grp;
    int o = off[n], d = cnt[n];
    float v = x[(size_t)n * C + c];
    int j = 0;
    for (; j + 4 <= d; j += 4) {
        int s0 = bucket[o + j], s1 = bucket[o + j + 1];
        int s2 = bucket[o + j + 2], s3 = bucket[o + j + 3];
        v += x[(size_t)s0 * C + c];
        v += x[(size_t)s1 * C + c];
        v += x[(size_t)s2 * C + c];
        v += x[(size_t)s3 * C + c];
    }
    for (; j < d; j++) v += x[(size_t)bucket[o + j] * C + c];
    g[(size_t)n * C + c] = v;
}

// ---------- phi ----------
__global__ __launch_bounds__(256) void phi1_k(const float* __restrict__ g,
                                              const float* __restrict__ w1,
                                              const float* __restrict__ b1,
                                              float* __restrict__ h1) {
    __shared__ float w1s[C * DPE];
    __shared__ float gs[4 * C];
    int t = threadIdx.x;
    int row0 = blockIdx.x * 4;
    #pragma unroll
    for (int q = 0; q < 4; q++) w1s[t + q * 256] = w1[t + q * 256];
    if (t < 64) gs[t] = g[row0 * C + t];
    __syncthreads();
    int r = t >> 6, j = t & 63;
    float h = b1[j];
    #pragma unroll
    for (int c = 0; c < C; c++) h = fmaf(gs[r * C + c], w1s[c * DPE + j], h);
    h1[(row0 + r) * DPE + j] = fmaxf(h, 0.0f);
}

__global__ __launch_bounds__(256) void phi2_k(const float* __restrict__ h1,
                                              const float* __restrict__ w2,
                                              const float* __restrict__ b2,
                                              float* __restrict__ out) {
    __shared__ float w2s[DPE * DPE];
    __shared__ float hs[4 * DPE];
    int t = threadIdx.x;
    int row0 = blockIdx.x * 4;
    #pragma unroll
    for (int q = 0; q < 16; q++) w2s[t + q * 256] = w2[t + q * 256];
    hs[t] = h1[row0 * DPE + t];
    __syncthreads();
    int r = t >> 6, d = t & 63;
    float o = b2[d];
    #pragma unroll
    for (int j = 0; j < DPE; j++) o = fmaf(hs[r * DPE + j], w2s[j * DPE + d], o);
    out[(row0 + r) * DPE + d] = o;
}

extern "C" void kernel_launch(void* const* d_in, const int* in_sizes, int n_in,
                              void* d_out, int out_size, void* d_ws, size_t ws_size,
                              hipStream_t stream) {
    const float* Lap   = (const float*)d_in[0];
    const float* W     = (const float*)d_in[1];
    const float* lin_w = (const float*)d_in[2];
    const float* lin_b = (const float*)d_in[3];
    const float* gam   = (const float*)d_in[4];
    const float* bet   = (const float*)d_in[5];
    const float* w1    = (const float*)d_in[6];
    const float* b1    = (const float*)d_in[7];
    const float* w2    = (const float*)d_in[8];
    const float* b2    = (const float*)d_in[9];
    const int*   ei    = (const int*)d_in[10];

    char* wsb = (char*)d_ws;
    float* feat  = (float*)wsb;                              // 64 MB
    uint4* Sf    = (uint4*)(wsb + ((size_t)64 << 20));       // 32 MB
    uint4* Pf    = (uint4*)(wsb + ((size_t)96 << 20));       // 8 MB (2 buffers)
    float* stats = (float*)(wsb + ((size_t)104 << 20));      // small tail region
    unsigned* bar = (unsigned*)(stats + 256);                // 8 counters, 128B apart
    float* x     = stats + 2048;
    float* g     = x + (size_t)NV * C;
    float* h1    = g + (size_t)NV * C;
    int*   cnt   = (int*)(h1 + (size_t)NV * DPE);
    int*   off   = cnt + NV;
    int*   cur   = off + NV;
    int*   bucket= cur + NV;                                 // NE ints
    float* out   = (float*)d_out;

    hipMemsetAsync(stats, 0, 8192, stream);                  // stats + bar
    hipMemsetAsync(cnt, 0, NV * sizeof(int), stream);
    prep_s<<<dim3(512), 256, 0, stream>>>(Lap, Sf);
    prep_w_plane<<<dim3(1024), 256, 0, stream>>>(W, feat);
    prep_w_frag<<<dim3(512), 256, 0, stream>>>(W, Pf);
    gemm_chain<<<dim3(256), 512, 0, stream>>>(Sf, Pf, Pf + PFBUF, feat, bar);
    bn_stats<<<dim3(1024), 256, 0, stream>>>(feat, lin_w, lin_b, stats);
    bn_x<<<dim3(256), 256, 0, stream>>>(feat, lin_w, lin_b, gam, bet, stats, x);
    edge_hist<<<dim3(NE / 256), 256, 0, stream>>>(ei, cnt);
    edge_scan<<<dim3(1), 256, 0, stream>>>(cnt, off, cur);
    edge_fill<<<dim3(NE / 256), 256, 0, stream>>>(ei, cur, bucket);
    edge_gather<<<dim3(NV / 16), 256, 0, stream>>>(cnt, off, bucket, x, g);
    phi1_k<<<dim3(2048), 256, 0, stream>>>(g, w1, b1, h1);
    phi2_k<<<dim3(2048), 256, 0, stream>>>(h1, w2, b2, out);
}

// Round 15
// 333.238 us; speedup vs baseline: 1.4523x; 1.4523x over previous
//
#include <hip/hip_runtime.h>

#define B 8
#define N 1024
#define M 128
#define KF 16
#define C 16
#define DPE 64
#define NE 131072
#define NV (B*N)
#define NM (N*M)
#define BN_EPS 1e-5f

typedef short bf16x8 __attribute__((ext_vector_type(8)));
typedef float f32x4 __attribute__((ext_vector_type(4)));

__device__ inline unsigned short f2bf_rne(float f) {
    unsigned u = __float_as_uint(f);
    u += 0x7fffu + ((u >> 16) & 1u);
    return (unsigned short)(u >> 16);
}
__device__ inline void split_bf16(float v, unsigned short& hi, unsigned short& lo) {
    hi = f2bf_rne(v);
    float hf = __uint_as_float((unsigned)hi << 16);
    lo = f2bf_rne(v - hf);
}
union U4 { uint4 v; unsigned short s[8]; };

// Sf frag-major (uint4 units): SF4(b,nsub,ks,hl,l) ; el = S[n=16nsub+(l&15)][k=32ks+8(l>>4)+j]
__device__ __host__ inline size_t SF4(int b, int nsub, int ks, int hl, int l) {
    return ((((size_t)b * 64 + nsub) * 32 + ks) * 2 + hl) * 64 + l;
}
// Pf frag-major (uint4 units) per buffer: PF4(b,msub,ks,hl,l)
__device__ __host__ inline size_t PF4(int b, int msub, int ks, int hl, int l) {
    return ((((size_t)b * 8 + msub) * 32 + ks) * 2 + hl) * 64 + l;
}
#define PFBUF ((size_t)B * 8 * 32 * 2 * 64)   // uint4 per Pf buffer (4MB)

// ---------- prep: S -> frag-major hi/lo bf16 (XCD-aligned: b = blk&7) ----------
__global__ __launch_bounds__(256) void prep_s(const float* __restrict__ Lap, uint4* __restrict__ Sf) {
    int b = blockIdx.x & 7, nb = blockIdx.x >> 3;
    int t = threadIdx.x;
    int nl = t >> 4, kg = t & 15;
    int n = nb * 16 + nl;
    const float* row = Lap + ((size_t)b * N + n) * N;
    #pragma unroll
    for (int jj = 0; jj < 8; jj++) {
        int koct = kg + 16 * jj;
        int k0 = koct * 8;
        float4 f0 = *(const float4*)(row + k0);
        float4 f1 = *(const float4*)(row + k0 + 4);
        float e[8] = {f0.x, f0.y, f0.z, f0.w, f1.x, f1.y, f1.z, f1.w};
        U4 hi, lo;
        #pragma unroll
        for (int j = 0; j < 8; j++) split_bf16(e[j], hi.s[j], lo.s[j]);
        int ks = k0 >> 5;
        int lf = nl + 16 * (koct & 3);
        Sf[SF4(b, nb, ks, 0, lf)] = hi.v;
        Sf[SF4(b, nb, ks, 1, lf)] = lo.v;
    }
}

// ---------- prep: W -> feat plane0 (W^T, [m][node]) (XCD-aligned) ----------
__global__ __launch_bounds__(256) void prep_w_plane(const float* __restrict__ W, float* __restrict__ feat) {
    __shared__ float T[32][33];
    int b = blockIdx.x & 7;
    int tile = blockIdx.x >> 3;
    int nt = tile & 31, mt = tile >> 5;
    int n0 = nt * 32, m0 = mt * 32;
    int t = threadIdx.x;
    {
        int nl = t >> 3, mq = t & 7;
        float4 v = *(const float4*)(W + ((size_t)b * N + n0 + nl) * M + m0 + mq * 4);
        T[nl][mq * 4 + 0] = v.x; T[nl][mq * 4 + 1] = v.y;
        T[nl][mq * 4 + 2] = v.z; T[nl][mq * 4 + 3] = v.w;
    }
    __syncthreads();
    {
        int ml = t >> 3, nq = t & 7;
        float4 v = make_float4(T[nq * 4 + 0][ml], T[nq * 4 + 1][ml], T[nq * 4 + 2][ml], T[nq * 4 + 3][ml]);
        float* plane = feat + (size_t)b * KF * NM;
        *(float4*)(plane + (size_t)(m0 + ml) * N + n0 + nq * 4) = v;
    }
}

// ---------- prep: W -> Pf buffer 0 (XCD-aligned) ----------
__global__ __launch_bounds__(256) void prep_w_frag(const float* __restrict__ W, uint4* __restrict__ Pf) {
    int b = blockIdx.x & 7;
    int r = (blockIdx.x >> 3) * 256 + threadIdx.x;
    int msub = r >> 11, ks = (r >> 6) & 31, l = r & 63;
    int m = 16 * msub + (l & 15);
    U4 hi, lo;
    #pragma unroll
    for (int j = 0; j < 8; j++) {
        int n = 32 * ks + 8 * (l >> 4) + j;
        float v = W[((size_t)b * N + n) * M + m];
        split_bf16(v, hi.s[j], lo.s[j]);
    }
    Pf[PF4(b, msub, ks, 0, l)] = hi.v;
    Pf[PF4(b, msub, ks, 1, l)] = lo.v;
}

// ---------- persistent MFMA chain, Sf LDS-resident ----------
// 256 blocks x 512 thr, b=blk&7 XCD-pinned (R8/R13-proven). Block's 128 KB Sf
// slice loaded into LDS ONCE, reused across all 15 steps (Sf HBM traffic /15).
// K-loop: zero barriers; wave w owns msub=w x 32 n, full K, 2-deep Pf register
// prefetch. Dynamic LDS 146 KB (needs hipFuncSetAttribute; 1 block/CU).
// Per-step sync = R13-proven per-batch relaxed spin + buffer_inv sc0 (L1-only).
__global__ __launch_bounds__(512) void gemm_chain(const uint4* __restrict__ Sf,
                                                  uint4* __restrict__ PfA,
                                                  uint4* __restrict__ PfB,
                                                  float* __restrict__ feat,
                                                  unsigned* bar) {
    extern __shared__ __align__(16) char smem[];
    uint4* ldsS = (uint4*)smem;               // 8192 uint4 = 128 KB
    float* Dl = (float*)(smem + 131072);      // 128 x 36 floats = 18.4 KB

    int b = blockIdx.x & 7, bx = blockIdx.x >> 3;   // XCD pinning
    int t = threadIdx.x;
    int w = t >> 6, lane = t & 63;
    size_t sbase = SF4(b, 2 * bx, 0, 0, 0);
    int n0 = 32 * bx;

    // one-time: Sf slice -> LDS (contiguous 8192 uint4)
    #pragma unroll
    for (int i = 0; i < 16; i++) ldsS[t + 512 * i] = Sf[sbase + t + 512 * i];
    __syncthreads();

    #pragma unroll 1
    for (int k = 0; k < KF - 1; k++) {
        const uint4* PfIn = (k & 1) ? PfB : PfA;
        uint4* PfOut      = (k & 1) ? PfA : PfB;
        const uint4* Pw = PfIn + (size_t)(b * 8 + w) * 4096;   // PF4(b,w,0,0,0)  [R14 bug: was /64 off]

        f32x4 acc0 = {}, acc1 = {};
        uint4 ah = Pw[lane], al = Pw[64 + lane];      // ks = 0
        #pragma unroll 4
        for (int ks = 0; ks < 32; ks++) {
            uint4 nh, nl2;
            if (ks < 31) {
                nh  = Pw[(size_t)(ks + 1) * 128 + lane];
                nl2 = Pw[(size_t)(ks + 1) * 128 + 64 + lane];
            }
            bf16x8 b0h = __builtin_bit_cast(bf16x8, ldsS[ks * 128 + lane]);
            bf16x8 b0l = __builtin_bit_cast(bf16x8, ldsS[ks * 128 + 64 + lane]);
            bf16x8 b1h = __builtin_bit_cast(bf16x8, ldsS[4096 + ks * 128 + lane]);
            bf16x8 b1l = __builtin_bit_cast(bf16x8, ldsS[4096 + ks * 128 + 64 + lane]);
            bf16x8 Ah = __builtin_bit_cast(bf16x8, ah);
            bf16x8 Al = __builtin_bit_cast(bf16x8, al);
            acc0 = __builtin_amdgcn_mfma_f32_16x16x32_bf16(Ah, b0h, acc0, 0, 0, 0);
            acc0 = __builtin_amdgcn_mfma_f32_16x16x32_bf16(Ah, b0l, acc0, 0, 0, 0);
            acc0 = __builtin_amdgcn_mfma_f32_16x16x32_bf16(Al, b0h, acc0, 0, 0, 0);
            acc1 = __builtin_amdgcn_mfma_f32_16x16x32_bf16(Ah, b1h, acc1, 0, 0, 0);
            acc1 = __builtin_amdgcn_mfma_f32_16x16x32_bf16(Ah, b1l, acc1, 0, 0, 0);
            acc1 = __builtin_amdgcn_mfma_f32_16x16x32_bf16(Al, b1h, acc1, 0, 0, 0);
            ah = nh; al = nl2;
        }

        // ---- epilogue: wave w owns Dl rows 16w..16w+15 ----
        #pragma unroll
        for (int r = 0; r < 4; r++) {
            int m = 16 * w + 4 * (lane >> 4) + r;
            Dl[m * 36 + (lane & 15)] = acc0[r];
            Dl[m * 36 + 16 + (lane & 15)] = acc1[r];
        }
        __syncthreads();
        {   // f32 plane write ([m][node]); 512 threads x 8 floats
            int m = t >> 2, c0 = (t & 3) * 8;
            float* plane = feat + ((size_t)b * KF + (k + 1)) * NM + (size_t)m * N + n0 + c0;
            ((float4*)plane)[0] = *(const float4*)&Dl[m * 36 + c0];
            ((float4*)plane)[1] = *(const float4*)&Dl[m * 36 + c0 + 4];
        }
        if (k < KF - 2) {
            {   // next-step A frags (hi/lo), ks = bx; msub = w (own rows)
                int l = t & 63;
                int m = 16 * w + (l & 15);
                int ncol = 8 * (l >> 4);
                float4 v0 = *(const float4*)&Dl[m * 36 + ncol];
                float4 v1 = *(const float4*)&Dl[m * 36 + ncol + 4];
                float e[8] = {v0.x, v0.y, v0.z, v0.w, v1.x, v1.y, v1.z, v1.w};
                U4 hi, lo;
                #pragma unroll
                for (int j = 0; j < 8; j++) split_bf16(e[j], hi.s[j], lo.s[j]);
                PfOut[PF4(b, w, bx, 0, l)] = hi.v;
                PfOut[PF4(b, w, bx, 1, l)] = lo.v;
            }
            // ---- per-batch (same-XCD) barrier: no fences, no L2 flush ----
            __syncthreads();   // drains all waves' Pf stores to L2 (vmcnt(0))
            if (t == 0) {
                __hip_atomic_fetch_add(&bar[b * 32], 1u, __ATOMIC_RELAXED,
                                       __HIP_MEMORY_SCOPE_AGENT);
                unsigned target = 32u * (unsigned)(k + 1);
                while (__hip_atomic_load(&bar[b * 32], __ATOMIC_RELAXED,
                                         __HIP_MEMORY_SCOPE_AGENT) < target)
                    __builtin_amdgcn_s_sleep(1);
            }
            __syncthreads();
            // invalidate this CU's vector L1 so Pf reads come from (fresh) L2
            asm volatile("buffer_inv sc0\n\ts_waitcnt vmcnt(0)" ::: "memory");
        } else {
            __syncthreads();
        }
    }
}

// ---------- BN stats (XCD-aligned) ----------
__global__ __launch_bounds__(256) void bn_stats(const float* __restrict__ feat,
                                                const float* __restrict__ lin_w,
                                                const float* __restrict__ lin_b,
                                                float* __restrict__ stats) {
    __shared__ float wls[KF * C];
    __shared__ float red[4][2][C];
    int t = threadIdx.x;
    wls[t] = lin_w[t];
    __syncthreads();
    int b = blockIdx.x & 7;
    int i = (blockIdx.x >> 3) * 256 + t;
    const float4* fb = (const float4*)(feat + (size_t)b * KF * NM);

    float4 hacc[C];
    #pragma unroll
    for (int c = 0; c < C; c++) {
        float bb = lin_b[c];
        hacc[c] = make_float4(bb, bb, bb, bb);
    }
    for (int kk = 0; kk < KF; kk++) {
        float4 pv = fb[(size_t)kk * (NM / 4) + i];
        #pragma unroll
        for (int c = 0; c < C; c++) {
            float wv = wls[kk * C + c];
            hacc[c].x = fmaf(pv.x, wv, hacc[c].x);
            hacc[c].y = fmaf(pv.y, wv, hacc[c].y);
            hacc[c].z = fmaf(pv.z, wv, hacc[c].z);
            hacc[c].w = fmaf(pv.w, wv, hacc[c].w);
        }
    }
    float s[C], ss[C];
    #pragma unroll
    for (int c = 0; c < C; c++) {
        float4 h = hacc[c];
        s[c] = h.x + h.y + h.z + h.w;
        ss[c] = h.x * h.x + h.y * h.y + h.z * h.z + h.w * h.w;
    }
    #pragma unroll
    for (int off = 32; off > 0; off >>= 1)
        #pragma unroll
        for (int c = 0; c < C; c++) {
            s[c] += __shfl_down(s[c], off);
            ss[c] += __shfl_down(ss[c], off);
        }
    if ((t & 63) == 0) {
        int wv = t >> 6;
        #pragma unroll
        for (int c = 0; c < C; c++) { red[wv][0][c] = s[c]; red[wv][1][c] = ss[c]; }
    }
    __syncthreads();
    if (t < 32) {
        int which = t >> 4, c = t & 15;
        float v = red[0][which][c] + red[1][which][c] + red[2][which][c] + red[3][which][c];
        atomicAdd(&stats[b * 32 + which * 16 + c], v);
    }
}

// ---------- BN apply + relu + mean over M -> x ----------
__global__ __launch_bounds__(256) void bn_x(const float* __restrict__ feat,
                                            const float* __restrict__ lin_w,
                                            const float* __restrict__ lin_b,
                                            const float* __restrict__ gam,
                                            const float* __restrict__ bet,
                                            const float* __restrict__ stats,
                                            float* __restrict__ x) {
    __shared__ float wls[KF * C];
    __shared__ float red[8][32 * 17];
    int t = threadIdx.x;
    wls[t] = lin_w[t];
    __syncthreads();
    int grp = blockIdx.x;
    int b = grp & 7, n0 = (grp >> 3) * 32;
    int nl = t & 31, mg = t >> 5;
    int n = n0 + nl;

    const float inv_nm = 1.0f / (float)NM;
    float sc[C], sh[C], bb[C];
    #pragma unroll
    for (int c = 0; c < C; c++) {
        float mean = stats[b * 32 + c] * inv_nm;
        float var = stats[b * 32 + 16 + c] * inv_nm - mean * mean;
        sc[c] = gam[c] * rsqrtf(var + BN_EPS);
        sh[c] = bet[c] - mean * sc[c];
        bb[c] = lin_b[c];
    }
    const float* fb = feat + (size_t)b * KF * NM + n;
    float y[C] = {};
    for (int m = mg * 16; m < mg * 16 + 16; m++) {
        float p[KF];
        #pragma unroll
        for (int kk = 0; kk < KF; kk++) p[kk] = fb[(size_t)kk * NM + (size_t)m * N];
        #pragma unroll
        for (int c = 0; c < C; c++) {
            float h = bb[c];
            #pragma unroll
            for (int kk = 0; kk < KF; kk++) h = fmaf(p[kk], wls[kk * C + c], h);
            y[c] += fmaxf(fmaf(h, sc[c], sh[c]), 0.0f);
        }
    }
    #pragma unroll
    for (int c = 0; c < C; c++) red[mg][nl * 17 + c] = y[c];
    __syncthreads();
    #pragma unroll
    for (int q = 0; q < 2; q++) {
        int slot = t + q * 256;
        int snl = slot >> 4, c = slot & 15;
        float v = 0.0f;
        #pragma unroll
        for (int m8 = 0; m8 < 8; m8++) v += red[m8][snl * 17 + c];
        v *= (1.0f / (float)M);
        x[((size_t)b * N + n0 + snl) * C + c] = v;
    }
}

// ---------- edge CSR build + gather ----------
__global__ __launch_bounds__(256) void edge_hist(const int* __restrict__ ei, int* __restrict__ cnt) {
    int e = blockIdx.x * 256 + threadIdx.x;
    bool is64 = (ei[1] == 0 && ei[3] == 0 && ei[5] == 0 && ei[7] == 0);
    int dst = is64 ? ei[2 * (NE + e)] : ei[NE + e];
    atomicAdd(&cnt[dst], 1);
}

__global__ __launch_bounds__(256) void edge_scan(const int* __restrict__ cnt,
                                                 int* __restrict__ off, int* __restrict__ cur) {
    __shared__ int ss[256];
    int t = threadIdx.x;
    int base = t * 32;
    int local[32];
    int s = 0;
    #pragma unroll
    for (int i = 0; i < 32; i++) { local[i] = cnt[base + i]; s += local[i]; }
    ss[t] = s;
    __syncthreads();
    #pragma unroll
    for (int d = 1; d < 256; d <<= 1) {
        int v = (t >= d) ? ss[t - d] : 0;
        __syncthreads();
        ss[t] += v;
        __syncthreads();
    }
    int excl = ss[t] - s;
    #pragma unroll
    for (int i = 0; i < 32; i++) { off[base + i] = excl; cur[base + i] = excl; excl += local[i]; }
}

__global__ __launch_bounds__(256) void edge_fill(const int* __restrict__ ei,
                                                 int* __restrict__ cur, int* __restrict__ bucket) {
    int e = blockIdx.x * 256 + threadIdx.x;
    bool is64 = (ei[1] == 0 && ei[3] == 0 && ei[5] == 0 && ei[7] == 0);
    int src, dst;
    if (is64) { src = ei[2 * e]; dst = ei[2 * (NE + e)]; }
    else      { src = ei[e];     dst = ei[NE + e]; }
    int pos = atomicAdd(&cur[dst], 1);
    bucket[pos] = src;
}

__global__ __launch_bounds__(256) void edge_gather(const int* __restrict__ cnt,
                                                   const int* __restrict__ off,
                                                   const int* __restrict__ bucket,
                                                   const float* __restrict__ x,
                                                   float* __restrict__ g) {
    int t = threadIdx.x;
    int grp = t >> 4, c = t & 15;
    int n = blockIdx.x * 16 + grp;
    int o = off[n], d = cnt[n];
    float v = x[(size_t)n * C + c];
    int j = 0;
    for (; j + 4 <= d; j += 4) {
        int s0 = bucket[o + j], s1 = bucket[o + j + 1];
        int s2 = bucket[o + j + 2], s3 = bucket[o + j + 3];
        v += x[(size_t)s0 * C + c];
        v += x[(size_t)s1 * C + c];
        v += x[(size_t)s2 * C + c];
        v += x[(size_t)s3 * C + c];
    }
    for (; j < d; j++) v += x[(size_t)bucket[o + j] * C + c];
    g[(size_t)n * C + c] = v;
}

// ---------- phi ----------
__global__ __launch_bounds__(256) void phi1_k(const float* __restrict__ g,
                                              const float* __restrict__ w1,
                                              const float* __restrict__ b1,
                                              float* __restrict__ h1) {
    __shared__ float w1s[C * DPE];
    __shared__ float gs[4 * C];
    int t = threadIdx.x;
    int row0 = blockIdx.x * 4;
    #pragma unroll
    for (int q = 0; q < 4; q++) w1s[t + q * 256] = w1[t + q * 256];
    if (t < 64) gs[t] = g[row0 * C + t];
    __syncthreads();
    int r = t >> 6, j = t & 63;
    float h = b1[j];
    #pragma unroll
    for (int c = 0; c < C; c++) h = fmaf(gs[r * C + c], w1s[c * DPE + j], h);
    h1[(row0 + r) * DPE + j] = fmaxf(h, 0.0f);
}

__global__ __launch_bounds__(256) void phi2_k(const float* __restrict__ h1,
                                              const float* __restrict__ w2,
                                              const float* __restrict__ b2,
                                              float* __restrict__ out) {
    __shared__ float w2s[DPE * DPE];
    __shared__ float hs[4 * DPE];
    int t = threadIdx.x;
    int row0 = blockIdx.x * 4;
    #pragma unroll
    for (int q = 0; q < 16; q++) w2s[t + q * 256] = w2[t + q * 256];
    hs[t] = h1[row0 * DPE + t];
    __syncthreads();
    int r = t >> 6, d = t & 63;
    float o = b2[d];
    #pragma unroll
    for (int j = 0; j < DPE; j++) o = fmaf(hs[r * DPE + j], w2s[j * DPE + d], o);
    out[(row0 + r) * DPE + d] = o;
}

extern "C" void kernel_launch(void* const* d_in, const int* in_sizes, int n_in,
                              void* d_out, int out_size, void* d_ws, size_t ws_size,
                              hipStream_t stream) {
    const float* Lap   = (const float*)d_in[0];
    const float* W     = (const float*)d_in[1];
    const float* lin_w = (const float*)d_in[2];
    const float* lin_b = (const float*)d_in[3];
    const float* gam   = (const float*)d_in[4];
    const float* bet   = (const float*)d_in[5];
    const float* w1    = (const float*)d_in[6];
    const float* b1    = (const float*)d_in[7];
    const float* w2    = (const float*)d_in[8];
    const float* b2    = (const float*)d_in[9];
    const int*   ei    = (const int*)d_in[10];

    char* wsb = (char*)d_ws;
    float* feat  = (float*)wsb;                              // 64 MB
    uint4* Sf    = (uint4*)(wsb + ((size_t)64 << 20));       // 32 MB
    uint4* Pf    = (uint4*)(wsb + ((size_t)96 << 20));       // 8 MB (2 buffers)
    float* stats = (float*)(wsb + ((size_t)104 << 20));      // small tail region
    unsigned* bar = (unsigned*)(stats + 256);                // 8 counters, 128B apart
    float* x     = stats + 2048;
    float* g     = x + (size_t)NV * C;
    float* h1    = g + (size_t)NV * C;
    int*   cnt   = (int*)(h1 + (size_t)NV * DPE);
    int*   off   = cnt + NV;
    int*   cur   = off + NV;
    int*   bucket= cur + NV;                                 // NE ints
    float* out   = (float*)d_out;

    // allow 146 KB dynamic LDS (default cap is 64 KB); idempotent host-side call
    static bool attr_set = false;
    if (!attr_set) {
        hipFuncSetAttribute((const void*)gemm_chain,
                            hipFuncAttributeMaxDynamicSharedMemorySize, 149504);
        attr_set = true;
    }

    hipMemsetAsync(stats, 0, 8192, stream);                  // stats + bar
    hipMemsetAsync(cnt, 0, NV * sizeof(int), stream);
    prep_s<<<dim3(512), 256, 0, stream>>>(Lap, Sf);
    prep_w_plane<<<dim3(1024), 256, 0, stream>>>(W, feat);
    prep_w_frag<<<dim3(512), 256, 0, stream>>>(W, Pf);
    gemm_chain<<<dim3(256), 512, 149504, stream>>>(Sf, Pf, Pf + PFBUF, feat, bar);
    bn_stats<<<dim3(1024), 256, 0, stream>>>(feat, lin_w, lin_b, stats);
    bn_x<<<dim3(256), 256, 0, stream>>>(feat, lin_w, lin_b, gam, bet, stats, x);
    edge_hist<<<dim3(NE / 256), 256, 0, stream>>>(ei, cnt);
    edge_scan<<<dim3(1), 256, 0, stream>>>(cnt, off, cur);
    edge_fill<<<dim3(NE / 256), 256, 0, stream>>>(ei, cur, bucket);
    edge_gather<<<dim3(NV / 16), 256, 0, stream>>>(cnt, off, bucket, x, g);
    phi1_k<<<dim3(2048), 256, 0, stream>>>(g, w1, b1, h1);
    phi2_k<<<dim3(2048), 256, 0, stream>>>(h1, w2, b2, out);
}

// Round 16
// 317.689 us; speedup vs baseline: 1.5234x; 1.0489x over previous
//
#include <hip/hip_runtime.h>

#define B 8
#define N 1024
#define M 128
#define KF 16
#define C 16
#define DPE 64
#define NE 131072
#define NV (B*N)
#define NM (N*M)
#define BN_EPS 1e-5f

typedef short bf16x8 __attribute__((ext_vector_type(8)));
typedef float f32x4 __attribute__((ext_vector_type(4)));

__device__ inline unsigned short f2bf_rne(float f) {
    unsigned u = __float_as_uint(f);
    u += 0x7fffu + ((u >> 16) & 1u);
    return (unsigned short)(u >> 16);
}
__device__ inline void split_bf16(float v, unsigned short& hi, unsigned short& lo) {
    hi = f2bf_rne(v);
    float hf = __uint_as_float((unsigned)hi << 16);
    lo = f2bf_rne(v - hf);
}
union U4 { uint4 v; unsigned short s[8]; };

// Sf frag-major (uint4 units): SF4(b,nsub,ks,hl,l) ; el = S[n=16nsub+(l&15)][k=32ks+8(l>>4)+j]
__device__ __host__ inline size_t SF4(int b, int nsub, int ks, int hl, int l) {
    return ((((size_t)b * 64 + nsub) * 32 + ks) * 2 + hl) * 64 + l;
}
// Pf frag-major (uint4 units) per buffer: PF4(b,msub,ks,hl,l)
__device__ __host__ inline size_t PF4(int b, int msub, int ks, int hl, int l) {
    return ((((size_t)b * 8 + msub) * 32 + ks) * 2 + hl) * 64 + l;
}
#define PFBUF ((size_t)B * 8 * 32 * 2 * 64)   // uint4 per Pf buffer (4MB)

// ---------- prep: S -> frag-major hi/lo bf16 (XCD-aligned: b = blk&7) ----------
__global__ __launch_bounds__(256) void prep_s(const float* __restrict__ Lap, uint4* __restrict__ Sf) {
    int b = blockIdx.x & 7, nb = blockIdx.x >> 3;
    int t = threadIdx.x;
    int nl = t >> 4, kg = t & 15;
    int n = nb * 16 + nl;
    const float* row = Lap + ((size_t)b * N + n) * N;
    #pragma unroll
    for (int jj = 0; jj < 8; jj++) {
        int koct = kg + 16 * jj;
        int k0 = koct * 8;
        float4 f0 = *(const float4*)(row + k0);
        float4 f1 = *(const float4*)(row + k0 + 4);
        float e[8] = {f0.x, f0.y, f0.z, f0.w, f1.x, f1.y, f1.z, f1.w};
        U4 hi, lo;
        #pragma unroll
        for (int j = 0; j < 8; j++) split_bf16(e[j], hi.s[j], lo.s[j]);
        int ks = k0 >> 5;
        int lf = nl + 16 * (koct & 3);
        Sf[SF4(b, nb, ks, 0, lf)] = hi.v;
        Sf[SF4(b, nb, ks, 1, lf)] = lo.v;
    }
}

// ---------- prep: W -> feat plane0 (W^T, [m][node]) (XCD-aligned) ----------
__global__ __launch_bounds__(256) void prep_w_plane(const float* __restrict__ W, float* __restrict__ feat) {
    __shared__ float T[32][33];
    int b = blockIdx.x & 7;
    int tile = blockIdx.x >> 3;
    int nt = tile & 31, mt = tile >> 5;
    int n0 = nt * 32, m0 = mt * 32;
    int t = threadIdx.x;
    {
        int nl = t >> 3, mq = t & 7;
        float4 v = *(const float4*)(W + ((size_t)b * N + n0 + nl) * M + m0 + mq * 4);
        T[nl][mq * 4 + 0] = v.x; T[nl][mq * 4 + 1] = v.y;
        T[nl][mq * 4 + 2] = v.z; T[nl][mq * 4 + 3] = v.w;
    }
    __syncthreads();
    {
        int ml = t >> 3, nq = t & 7;
        float4 v = make_float4(T[nq * 4 + 0][ml], T[nq * 4 + 1][ml], T[nq * 4 + 2][ml], T[nq * 4 + 3][ml]);
        float* plane = feat + (size_t)b * KF * NM;
        *(float4*)(plane + (size_t)(m0 + ml) * N + n0 + nq * 4) = v;
    }
}

// ---------- prep: W -> Pf buffer 0 (XCD-aligned) ----------
__global__ __launch_bounds__(256) void prep_w_frag(const float* __restrict__ W, uint4* __restrict__ Pf) {
    int b = blockIdx.x & 7;
    int r = (blockIdx.x >> 3) * 256 + threadIdx.x;
    int msub = r >> 11, ks = (r >> 6) & 31, l = r & 63;
    int m = 16 * msub + (l & 15);
    U4 hi, lo;
    #pragma unroll
    for (int j = 0; j < 8; j++) {
        int n = 32 * ks + 8 * (l >> 4) + j;
        float v = W[((size_t)b * N + n) * M + m];
        split_bf16(v, hi.s[j], lo.s[j]);
    }
    Pf[PF4(b, msub, ks, 0, l)] = hi.v;
    Pf[PF4(b, msub, ks, 1, l)] = lo.v;
}

// ---------- persistent MFMA chain, Sf LDS-resident ----------
// R15-proven structure (chain 172us, FETCH 20MB). Delta R16: 4-deep A-frag
// prefetch ring (8 loads in flight/wave ~= L2 latency coverage; VGPR was 40).
__global__ __launch_bounds__(512) void gemm_chain(const uint4* __restrict__ Sf,
                                                  uint4* __restrict__ PfA,
                                                  uint4* __restrict__ PfB,
                                                  float* __restrict__ feat,
                                                  unsigned* bar) {
    extern __shared__ __align__(16) char smem[];
    uint4* ldsS = (uint4*)smem;               // 8192 uint4 = 128 KB
    float* Dl = (float*)(smem + 131072);      // 128 x 36 floats = 18.4 KB

    int b = blockIdx.x & 7, bx = blockIdx.x >> 3;   // XCD pinning
    int t = threadIdx.x;
    int w = t >> 6, lane = t & 63;
    size_t sbase = SF4(b, 2 * bx, 0, 0, 0);
    int n0 = 32 * bx;

    // one-time: Sf slice -> LDS (contiguous 8192 uint4)
    #pragma unroll
    for (int i = 0; i < 16; i++) ldsS[t + 512 * i] = Sf[sbase + t + 512 * i];
    __syncthreads();

    #pragma unroll 1
    for (int k = 0; k < KF - 1; k++) {
        const uint4* PfIn = (k & 1) ? PfB : PfA;
        uint4* PfOut      = (k & 1) ? PfA : PfB;
        const uint4* Pw = PfIn + (size_t)(b * 8 + w) * 4096;   // PF4(b,w,0,0,0)

        f32x4 acc0 = {}, acc1 = {};
        uint4 ph[4], pl[4];                           // 4-deep prefetch ring
        #pragma unroll
        for (int q = 0; q < 4; q++) {
            ph[q] = Pw[(size_t)q * 128 + lane];
            pl[q] = Pw[(size_t)q * 128 + 64 + lane];
        }
        #pragma unroll 4
        for (int ks = 0; ks < 32; ks++) {
            uint4 ahu = ph[ks & 3], alu = pl[ks & 3];
            if (ks < 28) {
                ph[ks & 3] = Pw[(size_t)(ks + 4) * 128 + lane];
                pl[ks & 3] = Pw[(size_t)(ks + 4) * 128 + 64 + lane];
            }
            bf16x8 b0h = __builtin_bit_cast(bf16x8, ldsS[ks * 128 + lane]);
            bf16x8 b0l = __builtin_bit_cast(bf16x8, ldsS[ks * 128 + 64 + lane]);
            bf16x8 b1h = __builtin_bit_cast(bf16x8, ldsS[4096 + ks * 128 + lane]);
            bf16x8 b1l = __builtin_bit_cast(bf16x8, ldsS[4096 + ks * 128 + 64 + lane]);
            bf16x8 Ah = __builtin_bit_cast(bf16x8, ahu);
            bf16x8 Al = __builtin_bit_cast(bf16x8, alu);
            acc0 = __builtin_amdgcn_mfma_f32_16x16x32_bf16(Ah, b0h, acc0, 0, 0, 0);
            acc0 = __builtin_amdgcn_mfma_f32_16x16x32_bf16(Ah, b0l, acc0, 0, 0, 0);
            acc0 = __builtin_amdgcn_mfma_f32_16x16x32_bf16(Al, b0h, acc0, 0, 0, 0);
            acc1 = __builtin_amdgcn_mfma_f32_16x16x32_bf16(Ah, b1h, acc1, 0, 0, 0);
            acc1 = __builtin_amdgcn_mfma_f32_16x16x32_bf16(Ah, b1l, acc1, 0, 0, 0);
            acc1 = __builtin_amdgcn_mfma_f32_16x16x32_bf16(Al, b1h, acc1, 0, 0, 0);
        }

        // ---- epilogue: wave w owns Dl rows 16w..16w+15 ----
        #pragma unroll
        for (int r = 0; r < 4; r++) {
            int m = 16 * w + 4 * (lane >> 4) + r;
            Dl[m * 36 + (lane & 15)] = acc0[r];
            Dl[m * 36 + 16 + (lane & 15)] = acc1[r];
        }
        __syncthreads();
        {   // f32 plane write ([m][node]); 512 threads x 8 floats
            int m = t >> 2, c0 = (t & 3) * 8;
            float* plane = feat + ((size_t)b * KF + (k + 1)) * NM + (size_t)m * N + n0 + c0;
            ((float4*)plane)[0] = *(const float4*)&Dl[m * 36 + c0];
            ((float4*)plane)[1] = *(const float4*)&Dl[m * 36 + c0 + 4];
        }
        if (k < KF - 2) {
            {   // next-step A frags (hi/lo), ks = bx; msub = w (own rows)
                int l = t & 63;
                int m = 16 * w + (l & 15);
                int ncol = 8 * (l >> 4);
                float4 v0 = *(const float4*)&Dl[m * 36 + ncol];
                float4 v1 = *(const float4*)&Dl[m * 36 + ncol + 4];
                float e[8] = {v0.x, v0.y, v0.z, v0.w, v1.x, v1.y, v1.z, v1.w};
                U4 hi, lo;
                #pragma unroll
                for (int j = 0; j < 8; j++) split_bf16(e[j], hi.s[j], lo.s[j]);
                PfOut[PF4(b, w, bx, 0, l)] = hi.v;
                PfOut[PF4(b, w, bx, 1, l)] = lo.v;
            }
            // ---- per-batch (same-XCD) barrier: no fences, no L2 flush ----
            __syncthreads();   // drains all waves' Pf stores to L2 (vmcnt(0))
            if (t == 0) {
                __hip_atomic_fetch_add(&bar[b * 32], 1u, __ATOMIC_RELAXED,
                                       __HIP_MEMORY_SCOPE_AGENT);
                unsigned target = 32u * (unsigned)(k + 1);
                while (__hip_atomic_load(&bar[b * 32], __ATOMIC_RELAXED,
                                         __HIP_MEMORY_SCOPE_AGENT) < target)
                    __builtin_amdgcn_s_sleep(1);
            }
            __syncthreads();
            // invalidate this CU's vector L1 so Pf reads come from (fresh) L2
            asm volatile("buffer_inv sc0\n\ts_waitcnt vmcnt(0)" ::: "memory");
        } else {
            __syncthreads();
        }
    }
}

// ---------- BN stats (XCD-aligned) ----------
__global__ __launch_bounds__(256) void bn_stats(const float* __restrict__ feat,
                                                const float* __restrict__ lin_w,
                                                const float* __restrict__ lin_b,
                                                float* __restrict__ stats) {
    __shared__ float wls[KF * C];
    __shared__ float red[4][2][C];
    int t = threadIdx.x;
    wls[t] = lin_w[t];
    __syncthreads();
    int b = blockIdx.x & 7;
    int i = (blockIdx.x >> 3) * 256 + t;
    const float4* fb = (const float4*)(feat + (size_t)b * KF * NM);

    float4 hacc[C];
    #pragma unroll
    for (int c = 0; c < C; c++) {
        float bb = lin_b[c];
        hacc[c] = make_float4(bb, bb, bb, bb);
    }
    for (int kk = 0; kk < KF; kk++) {
        float4 pv = fb[(size_t)kk * (NM / 4) + i];
        #pragma unroll
        for (int c = 0; c < C; c++) {
            float wv = wls[kk * C + c];
            hacc[c].x = fmaf(pv.x, wv, hacc[c].x);
            hacc[c].y = fmaf(pv.y, wv, hacc[c].y);
            hacc[c].z = fmaf(pv.z, wv, hacc[c].z);
            hacc[c].w = fmaf(pv.w, wv, hacc[c].w);
        }
    }
    float s[C], ss[C];
    #pragma unroll
    for (int c = 0; c < C; c++) {
        float4 h = hacc[c];
        s[c] = h.x + h.y + h.z + h.w;
        ss[c] = h.x * h.x + h.y * h.y + h.z * h.z + h.w * h.w;
    }
    #pragma unroll
    for (int off = 32; off > 0; off >>= 1)
        #pragma unroll
        for (int c = 0; c < C; c++) {
            s[c] += __shfl_down(s[c], off);
            ss[c] += __shfl_down(ss[c], off);
        }
    if ((t & 63) == 0) {
        int wv = t >> 6;
        #pragma unroll
        for (int c = 0; c < C; c++) { red[wv][0][c] = s[c]; red[wv][1][c] = ss[c]; }
    }
    __syncthreads();
    if (t < 32) {
        int which = t >> 4, c = t & 15;
        float v = red[0][which][c] + red[1][which][c] + red[2][which][c] + red[3][which][c];
        atomicAdd(&stats[b * 32 + which * 16 + c], v);
    }
}

// ---------- BN apply + relu + mean over M -> x ----------
__global__ __launch_bounds__(256) void bn_x(const float* __restrict__ feat,
                                            const float* __restrict__ lin_w,
                                            const float* __restrict__ lin_b,
                                            const float* __restrict__ gam,
                                            const float* __restrict__ bet,
                                            const float* __restrict__ stats,
                                            float* __restrict__ x) {
    __shared__ float wls[KF * C];
    __shared__ float red[8][32 * 17];
    int t = threadIdx.x;
    wls[t] = lin_w[t];
    __syncthreads();
    int grp = blockIdx.x;
    int b = grp & 7, n0 = (grp >> 3) * 32;
    int nl = t & 31, mg = t >> 5;
    int n = n0 + nl;

    const float inv_nm = 1.0f / (float)NM;
    float sc[C], sh[C], bb[C];
    #pragma unroll
    for (int c = 0; c < C; c++) {
        float mean = stats[b * 32 + c] * inv_nm;
        float var = stats[b * 32 + 16 + c] * inv_nm - mean * mean;
        sc[c] = gam[c] * rsqrtf(var + BN_EPS);
        sh[c] = bet[c] - mean * sc[c];
        bb[c] = lin_b[c];
    }
    const float* fb = feat + (size_t)b * KF * NM + n;
    float y[C] = {};
    for (int m = mg * 16; m < mg * 16 + 16; m++) {
        float p[KF];
        #pragma unroll
        for (int kk = 0; kk < KF; kk++) p[kk] = fb[(size_t)kk * NM + (size_t)m * N];
        #pragma unroll
        for (int c = 0; c < C; c++) {
            float h = bb[c];
            #pragma unroll
            for (int kk = 0; kk < KF; kk++) h = fmaf(p[kk], wls[kk * C + c], h);
            y[c] += fmaxf(fmaf(h, sc[c], sh[c]), 0.0f);
        }
    }
    #pragma unroll
    for (int c = 0; c < C; c++) red[mg][nl * 17 + c] = y[c];
    __syncthreads();
    #pragma unroll
    for (int q = 0; q < 2; q++) {
        int slot = t + q * 256;
        int snl = slot >> 4, c = slot & 15;
        float v = 0.0f;
        #pragma unroll
        for (int m8 = 0; m8 < 8; m8++) v += red[m8][snl * 17 + c];
        v *= (1.0f / (float)M);
        x[((size_t)b * N + n0 + snl) * C + c] = v;
    }
}

// ---------- edge CSR build ----------
__global__ __launch_bounds__(256) void edge_hist(const int* __restrict__ ei, int* __restrict__ cnt) {
    int e = blockIdx.x * 256 + threadIdx.x;
    bool is64 = (ei[1] == 0 && ei[3] == 0 && ei[5] == 0 && ei[7] == 0);
    int dst = is64 ? ei[2 * (NE + e)] : ei[NE + e];
    atomicAdd(&cnt[dst], 1);
}

__global__ __launch_bounds__(256) void edge_scan(const int* __restrict__ cnt,
                                                 int* __restrict__ off, int* __restrict__ cur) {
    __shared__ int ss[256];
    int t = threadIdx.x;
    int base = t * 32;
    int local[32];
    int s = 0;
    #pragma unroll
    for (int i = 0; i < 32; i++) { local[i] = cnt[base + i]; s += local[i]; }
    ss[t] = s;
    __syncthreads();
    #pragma unroll
    for (int d = 1; d < 256; d <<= 1) {
        int v = (t >= d) ? ss[t - d] : 0;
        __syncthreads();
        ss[t] += v;
        __syncthreads();
    }
    int excl = ss[t] - s;
    #pragma unroll
    for (int i = 0; i < 32; i++) { off[base + i] = excl; cur[base + i] = excl; excl += local[i]; }
}

__global__ __launch_bounds__(256) void edge_fill(const int* __restrict__ ei,
                                                 int* __restrict__ cur, int* __restrict__ bucket) {
    int e = blockIdx.x * 256 + threadIdx.x;
    bool is64 = (ei[1] == 0 && ei[3] == 0 && ei[5] == 0 && ei[7] == 0);
    int src, dst;
    if (is64) { src = ei[2 * e]; dst = ei[2 * (NE + e)]; }
    else      { src = ei[e];     dst = ei[NE + e]; }
    int pos = atomicAdd(&cur[dst], 1);
    bucket[pos] = src;
}

// ---------- fused gather + phi1 + phi2 (correctness-validated in R10) ----------
__global__ __launch_bounds__(256) void phi_fused(const int* __restrict__ cnt,
                                                 const int* __restrict__ off,
                                                 const int* __restrict__ bucket,
                                                 const float* __restrict__ x,
                                                 const float* __restrict__ w1,
                                                 const float* __restrict__ b1,
                                                 const float* __restrict__ w2,
                                                 const float* __restrict__ b2,
                                                 float* __restrict__ out) {
    __shared__ float w1s[C * DPE];
    __shared__ float w2s[DPE * DPE];
    __shared__ float b2s[DPE];
    __shared__ float gsh[16][17];
    __shared__ float h1sh[16][DPE];
    int t = threadIdx.x;
    #pragma unroll
    for (int q = 0; q < 4; q++) w1s[t + q * 256] = w1[t + q * 256];
    #pragma unroll
    for (int q = 0; q < 16; q++) w2s[t + q * 256] = w2[t + q * 256];
    if (t < DPE) b2s[t] = b2[t];

    {   // gather: node nl, channel c
        int nl = t >> 4, c = t & 15;
        int n = blockIdx.x * 16 + nl;
        int o = off[n], d = cnt[n];
        float v = x[(size_t)n * C + c];
        int j = 0;
        for (; j + 4 <= d; j += 4) {
            int s0 = bucket[o + j], s1 = bucket[o + j + 1];
            int s2 = bucket[o + j + 2], s3 = bucket[o + j + 3];
            v += x[(size_t)s0 * C + c];
            v += x[(size_t)s1 * C + c];
            v += x[(size_t)s2 * C + c];
            v += x[(size_t)s3 * C + c];
        }
        for (; j < d; j++) v += x[(size_t)bucket[o + j] * C + c];
        gsh[nl][c] = v;
    }
    __syncthreads();
    #pragma unroll
    for (int q = 0; q < 4; q++) {       // phi1: 16 nodes x 64
        int item = t + 256 * q;
        int node = item >> 6, j = item & 63;
        float h = b1[j];
        #pragma unroll
        for (int c = 0; c < C; c++) h = fmaf(gsh[node][c], w1s[c * DPE + j], h);
        h1sh[node][j] = fmaxf(h, 0.0f);
    }
    __syncthreads();
    #pragma unroll
    for (int q = 0; q < 4; q++) {       // phi2: 16 nodes x 64
        int item = t + 256 * q;
        int node = item >> 6, d = item & 63;
        float o2 = b2s[d];
        #pragma unroll
        for (int j = 0; j < DPE; j++) o2 = fmaf(h1sh[node][j], w2s[j * DPE + d], o2);
        out[((size_t)blockIdx.x * 16 + node) * DPE + d] = o2;
    }
}

extern "C" void kernel_launch(void* const* d_in, const int* in_sizes, int n_in,
                              void* d_out, int out_size, void* d_ws, size_t ws_size,
                              hipStream_t stream) {
    const float* Lap   = (const float*)d_in[0];
    const float* W     = (const float*)d_in[1];
    const float* lin_w = (const float*)d_in[2];
    const float* lin_b = (const float*)d_in[3];
    const float* gam   = (const float*)d_in[4];
    const float* bet   = (const float*)d_in[5];
    const float* w1    = (const float*)d_in[6];
    const float* b1    = (const float*)d_in[7];
    const float* w2    = (const float*)d_in[8];
    const float* b2    = (const float*)d_in[9];
    const int*   ei    = (const int*)d_in[10];

    char* wsb = (char*)d_ws;
    float* feat  = (float*)wsb;                              // 64 MB
    uint4* Sf    = (uint4*)(wsb + ((size_t)64 << 20));       // 32 MB
    uint4* Pf    = (uint4*)(wsb + ((size_t)96 << 20));       // 8 MB (2 buffers)
    float* stats = (float*)(wsb + ((size_t)104 << 20));      // small tail region
    unsigned* bar = (unsigned*)(stats + 256);                // 8 counters, 128B apart
    float* x     = stats + 2048;
    int*   cnt   = (int*)(x + (size_t)NV * C);
    int*   off   = cnt + NV;
    int*   cur   = off + NV;
    int*   bucket= cur + NV;                                 // NE ints
    float* out   = (float*)d_out;

    // allow 146 KB dynamic LDS (default cap is 64 KB); idempotent host-side call
    static bool attr_set = false;
    if (!attr_set) {
        hipFuncSetAttribute((const void*)gemm_chain,
                            hipFuncAttributeMaxDynamicSharedMemorySize, 149504);
        attr_set = true;
    }

    hipMemsetAsync(stats, 0, 8192, stream);                  // stats + bar
    hipMemsetAsync(cnt, 0, NV * sizeof(int), stream);
    prep_s<<<dim3(512), 256, 0, stream>>>(Lap, Sf);
    prep_w_plane<<<dim3(1024), 256, 0, stream>>>(W, feat);
    prep_w_frag<<<dim3(512), 256, 0, stream>>>(W, Pf);
    gemm_chain<<<dim3(256), 512, 149504, stream>>>(Sf, Pf, Pf + PFBUF, feat, bar);
    bn_stats<<<dim3(1024), 256, 0, stream>>>(feat, lin_w, lin_b, stats);
    bn_x<<<dim3(256), 256, 0, stream>>>(feat, lin_w, lin_b, gam, bet, stats, x);
    edge_hist<<<dim3(NE / 256), 256, 0, stream>>>(ei, cnt);
    edge_scan<<<dim3(1), 256, 0, stream>>>(cnt, off, cur);
    edge_fill<<<dim3(NE / 256), 256, 0, stream>>>(ei, cur, bucket);
    phi_fused<<<dim3(NV / 16), 256, 0, stream>>>(cnt, off, bucket, x, w1, b1, w2, b2, out);
}

// Round 17
// 313.673 us; speedup vs baseline: 1.5429x; 1.0128x over previous
//
#include <hip/hip_runtime.h>

#define B 8
#define N 1024
#define M 128
#define KF 16
#define C 16
#define DPE 64
#define NE 131072
#define NV (B*N)
#define NM (N*M)
#define BN_EPS 1e-5f

typedef short bf16x8 __attribute__((ext_vector_type(8)));
typedef float f32x4 __attribute__((ext_vector_type(4)));

__device__ inline unsigned short f2bf_rne(float f) {
    unsigned u = __float_as_uint(f);
    u += 0x7fffu + ((u >> 16) & 1u);
    return (unsigned short)(u >> 16);
}
__device__ inline void split_bf16(float v, unsigned short& hi, unsigned short& lo) {
    hi = f2bf_rne(v);
    float hf = __uint_as_float((unsigned)hi << 16);
    lo = f2bf_rne(v - hf);
}
union U4 { uint4 v; unsigned short s[8]; };

// Sf frag-major (uint4 units): SF4(b,nsub,ks,hl,l) ; el = S[n=16nsub+(l&15)][k=32ks+8(l>>4)+j]
__device__ __host__ inline size_t SF4(int b, int nsub, int ks, int hl, int l) {
    return ((((size_t)b * 64 + nsub) * 32 + ks) * 2 + hl) * 64 + l;
}
// Pf frag-major (uint4 units) per buffer: PF4(b,msub,ks,hl,l)
__device__ __host__ inline size_t PF4(int b, int msub, int ks, int hl, int l) {
    return ((((size_t)b * 8 + msub) * 32 + ks) * 2 + hl) * 64 + l;
}
#define PFBUF ((size_t)B * 8 * 32 * 2 * 64)   // uint4 per Pf buffer (4MB)

// ---------- prep: S -> frag-major hi/lo bf16 (XCD-aligned: b = blk&7) ----------
__global__ __launch_bounds__(256) void prep_s(const float* __restrict__ Lap, uint4* __restrict__ Sf) {
    int b = blockIdx.x & 7, nb = blockIdx.x >> 3;
    int t = threadIdx.x;
    int nl = t >> 4, kg = t & 15;
    int n = nb * 16 + nl;
    const float* row = Lap + ((size_t)b * N + n) * N;
    #pragma unroll
    for (int jj = 0; jj < 8; jj++) {
        int koct = kg + 16 * jj;
        int k0 = koct * 8;
        float4 f0 = *(const float4*)(row + k0);
        float4 f1 = *(const float4*)(row + k0 + 4);
        float e[8] = {f0.x, f0.y, f0.z, f0.w, f1.x, f1.y, f1.z, f1.w};
        U4 hi, lo;
        #pragma unroll
        for (int j = 0; j < 8; j++) split_bf16(e[j], hi.s[j], lo.s[j]);
        int ks = k0 >> 5;
        int lf = nl + 16 * (koct & 3);
        Sf[SF4(b, nb, ks, 0, lf)] = hi.v;
        Sf[SF4(b, nb, ks, 1, lf)] = lo.v;
    }
}

// ---------- prep: W -> feat plane0 (W^T, [m][node]) (XCD-aligned) ----------
__global__ __launch_bounds__(256) void prep_w_plane(const float* __restrict__ W, float* __restrict__ feat) {
    __shared__ float T[32][33];
    int b = blockIdx.x & 7;
    int tile = blockIdx.x >> 3;
    int nt = tile & 31, mt = tile >> 5;
    int n0 = nt * 32, m0 = mt * 32;
    int t = threadIdx.x;
    {
        int nl = t >> 3, mq = t & 7;
        float4 v = *(const float4*)(W + ((size_t)b * N + n0 + nl) * M + m0 + mq * 4);
        T[nl][mq * 4 + 0] = v.x; T[nl][mq * 4 + 1] = v.y;
        T[nl][mq * 4 + 2] = v.z; T[nl][mq * 4 + 3] = v.w;
    }
    __syncthreads();
    {
        int ml = t >> 3, nq = t & 7;
        float4 v = make_float4(T[nq * 4 + 0][ml], T[nq * 4 + 1][ml], T[nq * 4 + 2][ml], T[nq * 4 + 3][ml]);
        float* plane = feat + (size_t)b * KF * NM;
        *(float4*)(plane + (size_t)(m0 + ml) * N + n0 + nq * 4) = v;
    }
}

// ---------- prep: W -> Pf buffer 0 (XCD-aligned) ----------
__global__ __launch_bounds__(256) void prep_w_frag(const float* __restrict__ W, uint4* __restrict__ Pf) {
    int b = blockIdx.x & 7;
    int r = (blockIdx.x >> 3) * 256 + threadIdx.x;
    int msub = r >> 11, ks = (r >> 6) & 31, l = r & 63;
    int m = 16 * msub + (l & 15);
    U4 hi, lo;
    #pragma unroll
    for (int j = 0; j < 8; j++) {
        int n = 32 * ks + 8 * (l >> 4) + j;
        float v = W[((size_t)b * N + n) * M + m];
        split_bf16(v, hi.s[j], lo.s[j]);
    }
    Pf[PF4(b, msub, ks, 0, l)] = hi.v;
    Pf[PF4(b, msub, ks, 1, l)] = lo.v;
}

// ---------- persistent MFMA chain, Sf LDS-resident ----------
// R16 base (chain 159us) + split-K 2-msub waves: wave w -> K-half g=w>>2,
// msubs {2wq, 2wq+1} (wq=w&3). Each B-fragment LDS read feeds 2 msubs ->
// LDS volume per CU per step halves (1MB -> 512KB, the binding pipe).
// K-half reduction runs through Dl itself (+1 barrier only).
__global__ __launch_bounds__(512) void gemm_chain(const uint4* __restrict__ Sf,
                                                  uint4* __restrict__ PfA,
                                                  uint4* __restrict__ PfB,
                                                  float* __restrict__ feat,
                                                  unsigned* bar) {
    extern __shared__ __align__(16) char smem[];
    uint4* ldsS = (uint4*)smem;               // 8192 uint4 = 128 KB
    float* Dl = (float*)(smem + 131072);      // 128 x 36 floats = 18.4 KB

    int b = blockIdx.x & 7, bx = blockIdx.x >> 3;   // XCD pinning
    int t = threadIdx.x;
    int w = t >> 6, lane = t & 63;
    int g = w >> 2, wq = w & 3;               // K-half, msub-pair
    size_t sbase = SF4(b, 2 * bx, 0, 0, 0);
    int n0 = 32 * bx;

    // one-time: Sf slice -> LDS (contiguous 8192 uint4)
    #pragma unroll
    for (int i = 0; i < 16; i++) ldsS[t + 512 * i] = Sf[sbase + t + 512 * i];
    __syncthreads();

    #pragma unroll 1
    for (int k = 0; k < KF - 1; k++) {
        const uint4* PfIn = (k & 1) ? PfB : PfA;
        uint4* PfOut      = (k & 1) ? PfA : PfB;
        const uint4* Pw0 = PfIn + (size_t)(b * 8 + 2 * wq) * 4096 + (size_t)(16 * g) * 128;
        const uint4* Pw1 = Pw0 + 4096;

        f32x4 acc[2][2] = {};                 // [mi][ni]
        uint4 ph[2][2], pl[2][2];             // [ring][mi], 2-deep x 4 = 8 in flight
        #pragma unroll
        for (int q = 0; q < 2; q++) {
            ph[q][0] = Pw0[(size_t)q * 128 + lane];
            pl[q][0] = Pw0[(size_t)q * 128 + 64 + lane];
            ph[q][1] = Pw1[(size_t)q * 128 + lane];
            pl[q][1] = Pw1[(size_t)q * 128 + 64 + lane];
        }
        #pragma unroll 2
        for (int ks = 0; ks < 16; ks++) {
            int kg = 16 * g + ks;
            uint4 a0h = ph[ks & 1][0], a0l = pl[ks & 1][0];
            uint4 a1h = ph[ks & 1][1], a1l = pl[ks & 1][1];
            if (ks < 14) {
                ph[ks & 1][0] = Pw0[(size_t)(ks + 2) * 128 + lane];
                pl[ks & 1][0] = Pw0[(size_t)(ks + 2) * 128 + 64 + lane];
                ph[ks & 1][1] = Pw1[(size_t)(ks + 2) * 128 + lane];
                pl[ks & 1][1] = Pw1[(size_t)(ks + 2) * 128 + 64 + lane];
            }
            bf16x8 b0h = __builtin_bit_cast(bf16x8, ldsS[kg * 128 + lane]);
            bf16x8 b0l = __builtin_bit_cast(bf16x8, ldsS[kg * 128 + 64 + lane]);
            bf16x8 b1h = __builtin_bit_cast(bf16x8, ldsS[4096 + kg * 128 + lane]);
            bf16x8 b1l = __builtin_bit_cast(bf16x8, ldsS[4096 + kg * 128 + 64 + lane]);
            bf16x8 A0h = __builtin_bit_cast(bf16x8, a0h);
            bf16x8 A0l = __builtin_bit_cast(bf16x8, a0l);
            bf16x8 A1h = __builtin_bit_cast(bf16x8, a1h);
            bf16x8 A1l = __builtin_bit_cast(bf16x8, a1l);
            acc[0][0] = __builtin_amdgcn_mfma_f32_16x16x32_bf16(A0h, b0h, acc[0][0], 0, 0, 0);
            acc[0][0] = __builtin_amdgcn_mfma_f32_16x16x32_bf16(A0h, b0l, acc[0][0], 0, 0, 0);
            acc[0][0] = __builtin_amdgcn_mfma_f32_16x16x32_bf16(A0l, b0h, acc[0][0], 0, 0, 0);
            acc[0][1] = __builtin_amdgcn_mfma_f32_16x16x32_bf16(A0h, b1h, acc[0][1], 0, 0, 0);
            acc[0][1] = __builtin_amdgcn_mfma_f32_16x16x32_bf16(A0h, b1l, acc[0][1], 0, 0, 0);
            acc[0][1] = __builtin_amdgcn_mfma_f32_16x16x32_bf16(A0l, b1h, acc[0][1], 0, 0, 0);
            acc[1][0] = __builtin_amdgcn_mfma_f32_16x16x32_bf16(A1h, b0h, acc[1][0], 0, 0, 0);
            acc[1][0] = __builtin_amdgcn_mfma_f32_16x16x32_bf16(A1h, b0l, acc[1][0], 0, 0, 0);
            acc[1][0] = __builtin_amdgcn_mfma_f32_16x16x32_bf16(A1l, b0h, acc[1][0], 0, 0, 0);
            acc[1][1] = __builtin_amdgcn_mfma_f32_16x16x32_bf16(A1h, b1h, acc[1][1], 0, 0, 0);
            acc[1][1] = __builtin_amdgcn_mfma_f32_16x16x32_bf16(A1h, b1l, acc[1][1], 0, 0, 0);
            acc[1][1] = __builtin_amdgcn_mfma_f32_16x16x32_bf16(A1l, b1h, acc[1][1], 0, 0, 0);
        }

        // ---- K-half reduction through Dl: g=1 writes, g=0 adds ----
        if (g == 1) {
            #pragma unroll
            for (int mi = 0; mi < 2; mi++)
                #pragma unroll
                for (int ni = 0; ni < 2; ni++)
                    #pragma unroll
                    for (int r = 0; r < 4; r++) {
                        int m = 32 * wq + 16 * mi + 4 * (lane >> 4) + r;
                        int c = 16 * ni + (lane & 15);
                        Dl[m * 36 + c] = acc[mi][ni][r];
                    }
        }
        __syncthreads();
        if (g == 0) {
            #pragma unroll
            for (int mi = 0; mi < 2; mi++)
                #pragma unroll
                for (int ni = 0; ni < 2; ni++)
                    #pragma unroll
                    for (int r = 0; r < 4; r++) {
                        int m = 32 * wq + 16 * mi + 4 * (lane >> 4) + r;
                        int c = 16 * ni + (lane & 15);
                        Dl[m * 36 + c] += acc[mi][ni][r];
                    }
        }
        __syncthreads();
        {   // f32 plane write ([m][node]); 512 threads x 8 floats
            int m = t >> 2, c0 = (t & 3) * 8;
            float* plane = feat + ((size_t)b * KF + (k + 1)) * NM + (size_t)m * N + n0 + c0;
            ((float4*)plane)[0] = *(const float4*)&Dl[m * 36 + c0];
            ((float4*)plane)[1] = *(const float4*)&Dl[m * 36 + c0 + 4];
        }
        if (k < KF - 2) {
            {   // next-step A frags (hi/lo), ks = bx; msub = w
                int l = t & 63;
                int m = 16 * w + (l & 15);
                int ncol = 8 * (l >> 4);
                float4 v0 = *(const float4*)&Dl[m * 36 + ncol];
                float4 v1 = *(const float4*)&Dl[m * 36 + ncol + 4];
                float e[8] = {v0.x, v0.y, v0.z, v0.w, v1.x, v1.y, v1.z, v1.w};
                U4 hi, lo;
                #pragma unroll
                for (int j = 0; j < 8; j++) split_bf16(e[j], hi.s[j], lo.s[j]);
                PfOut[PF4(b, w, bx, 0, l)] = hi.v;
                PfOut[PF4(b, w, bx, 1, l)] = lo.v;
            }
            // ---- per-batch (same-XCD) barrier: no fences, no L2 flush ----
            __syncthreads();   // drains all waves' Pf stores to L2 (vmcnt(0))
            if (t == 0) {
                __hip_atomic_fetch_add(&bar[b * 32], 1u, __ATOMIC_RELAXED,
                                       __HIP_MEMORY_SCOPE_AGENT);
                unsigned target = 32u * (unsigned)(k + 1);
                while (__hip_atomic_load(&bar[b * 32], __ATOMIC_RELAXED,
                                         __HIP_MEMORY_SCOPE_AGENT) < target)
                    __builtin_amdgcn_s_sleep(1);
            }
            __syncthreads();
            // invalidate this CU's vector L1 so Pf reads come from (fresh) L2
            asm volatile("buffer_inv sc0\n\ts_waitcnt vmcnt(0)" ::: "memory");
        } else {
            __syncthreads();
        }
    }
}

// ---------- BN stats (XCD-aligned) ----------
__global__ __launch_bounds__(256) void bn_stats(const float* __restrict__ feat,
                                                const float* __restrict__ lin_w,
                                                const float* __restrict__ lin_b,
                                                float* __restrict__ stats) {
    __shared__ float wls[KF * C];
    __shared__ float red[4][2][C];
    int t = threadIdx.x;
    wls[t] = lin_w[t];
    __syncthreads();
    int b = blockIdx.x & 7;
    int i = (blockIdx.x >> 3) * 256 + t;
    const float4* fb = (const float4*)(feat + (size_t)b * KF * NM);

    float4 hacc[C];
    #pragma unroll
    for (int c = 0; c < C; c++) {
        float bb = lin_b[c];
        hacc[c] = make_float4(bb, bb, bb, bb);
    }
    for (int kk = 0; kk < KF; kk++) {
        float4 pv = fb[(size_t)kk * (NM / 4) + i];
        #pragma unroll
        for (int c = 0; c < C; c++) {
            float wv = wls[kk * C + c];
            hacc[c].x = fmaf(pv.x, wv, hacc[c].x);
            hacc[c].y = fmaf(pv.y, wv, hacc[c].y);
            hacc[c].z = fmaf(pv.z, wv, hacc[c].z);
            hacc[c].w = fmaf(pv.w, wv, hacc[c].w);
        }
    }
    float s[C], ss[C];
    #pragma unroll
    for (int c = 0; c < C; c++) {
        float4 h = hacc[c];
        s[c] = h.x + h.y + h.z + h.w;
        ss[c] = h.x * h.x + h.y * h.y + h.z * h.z + h.w * h.w;
    }
    #pragma unroll
    for (int off = 32; off > 0; off >>= 1)
        #pragma unroll
        for (int c = 0; c < C; c++) {
            s[c] += __shfl_down(s[c], off);
            ss[c] += __shfl_down(ss[c], off);
        }
    if ((t & 63) == 0) {
        int wv = t >> 6;
        #pragma unroll
        for (int c = 0; c < C; c++) { red[wv][0][c] = s[c]; red[wv][1][c] = ss[c]; }
    }
    __syncthreads();
    if (t < 32) {
        int which = t >> 4, c = t & 15;
        float v = red[0][which][c] + red[1][which][c] + red[2][which][c] + red[3][which][c];
        atomicAdd(&stats[b * 32 + which * 16 + c], v);
    }
}

// ---------- BN apply + relu + mean over M -> x ----------
__global__ __launch_bounds__(256) void bn_x(const float* __restrict__ feat,
                                            const float* __restrict__ lin_w,
                                            const float* __restrict__ lin_b,
                                            const float* __restrict__ gam,
                                            const float* __restrict__ bet,
                                            const float* __restrict__ stats,
                                            float* __restrict__ x) {
    __shared__ float wls[KF * C];
    __shared__ float red[8][32 * 17];
    int t = threadIdx.x;
    wls[t] = lin_w[t];
    __syncthreads();
    int grp = blockIdx.x;
    int b = grp & 7, n0 = (grp >> 3) * 32;
    int nl = t & 31, mg = t >> 5;
    int n = n0 + nl;

    const float inv_nm = 1.0f / (float)NM;
    float sc[C], sh[C], bb[C];
    #pragma unroll
    for (int c = 0; c < C; c++) {
        float mean = stats[b * 32 + c] * inv_nm;
        float var = stats[b * 32 + 16 + c] * inv_nm - mean * mean;
        sc[c] = gam[c] * rsqrtf(var + BN_EPS);
        sh[c] = bet[c] - mean * sc[c];
        bb[c] = lin_b[c];
    }
    const float* fb = feat + (size_t)b * KF * NM + n;
    float y[C] = {};
    for (int m = mg * 16; m < mg * 16 + 16; m++) {
        float p[KF];
        #pragma unroll
        for (int kk = 0; kk < KF; kk++) p[kk] = fb[(size_t)kk * NM + (size_t)m * N];
        #pragma unroll
        for (int c = 0; c < C; c++) {
            float h = bb[c];
            #pragma unroll
            for (int kk = 0; kk < KF; kk++) h = fmaf(p[kk], wls[kk * C + c], h);
            y[c] += fmaxf(fmaf(h, sc[c], sh[c]), 0.0f);
        }
    }
    #pragma unroll
    for (int c = 0; c < C; c++) red[mg][nl * 17 + c] = y[c];
    __syncthreads();
    #pragma unroll
    for (int q = 0; q < 2; q++) {
        int slot = t + q * 256;
        int snl = slot >> 4, c = slot & 15;
        float v = 0.0f;
        #pragma unroll
        for (int m8 = 0; m8 < 8; m8++) v += red[m8][snl * 17 + c];
        v *= (1.0f / (float)M);
        x[((size_t)b * N + n0 + snl) * C + c] = v;
    }
}

// ---------- edge CSR build ----------
__global__ __launch_bounds__(256) void edge_hist(const int* __restrict__ ei, int* __restrict__ cnt) {
    int e = blockIdx.x * 256 + threadIdx.x;
    bool is64 = (ei[1] == 0 && ei[3] == 0 && ei[5] == 0 && ei[7] == 0);
    int dst = is64 ? ei[2 * (NE + e)] : ei[NE + e];
    atomicAdd(&cnt[dst], 1);
}

__global__ __launch_bounds__(256) void edge_scan(const int* __restrict__ cnt,
                                                 int* __restrict__ off, int* __restrict__ cur) {
    __shared__ int ss[256];
    int t = threadIdx.x;
    int base = t * 32;
    int local[32];
    int s = 0;
    #pragma unroll
    for (int i = 0; i < 32; i++) { local[i] = cnt[base + i]; s += local[i]; }
    ss[t] = s;
    __syncthreads();
    #pragma unroll
    for (int d = 1; d < 256; d <<= 1) {
        int v = (t >= d) ? ss[t - d] : 0;
        __syncthreads();
        ss[t] += v;
        __syncthreads();
    }
    int excl = ss[t] - s;
    #pragma unroll
    for (int i = 0; i < 32; i++) { off[base + i] = excl; cur[base + i] = excl; excl += local[i]; }
}

__global__ __launch_bounds__(256) void edge_fill(const int* __restrict__ ei,
                                                 int* __restrict__ cur, int* __restrict__ bucket) {
    int e = blockIdx.x * 256 + threadIdx.x;
    bool is64 = (ei[1] == 0 && ei[3] == 0 && ei[5] == 0 && ei[7] == 0);
    int src, dst;
    if (is64) { src = ei[2 * e]; dst = ei[2 * (NE + e)]; }
    else      { src = ei[e];     dst = ei[NE + e]; }
    int pos = atomicAdd(&cur[dst], 1);
    bucket[pos] = src;
}

// ---------- fused gather + phi1 + phi2 ----------
__global__ __launch_bounds__(256) void phi_fused(const int* __restrict__ cnt,
                                                 const int* __restrict__ off,
                                                 const int* __restrict__ bucket,
                                                 const float* __restrict__ x,
                                                 const float* __restrict__ w1,
                                                 const float* __restrict__ b1,
                                                 const float* __restrict__ w2,
                                                 const float* __restrict__ b2,
                                                 float* __restrict__ out) {
    __shared__ float w1s[C * DPE];
    __shared__ float w2s[DPE * DPE];
    __shared__ float b2s[DPE];
    __shared__ float gsh[16][17];
    __shared__ float h1sh[16][DPE];
    int t = threadIdx.x;
    #pragma unroll
    for (int q = 0; q < 4; q++) w1s[t + q * 256] = w1[t + q * 256];
    #pragma unroll
    for (int q = 0; q < 16; q++) w2s[t + q * 256] = w2[t + q * 256];
    if (t < DPE) b2s[t] = b2[t];

    {   // gather: node nl, channel c
        int nl = t >> 4, c = t & 15;
        int n = blockIdx.x * 16 + nl;
        int o = off[n], d = cnt[n];
        float v = x[(size_t)n * C + c];
        int j = 0;
        for (; j + 4 <= d; j += 4) {
            int s0 = bucket[o + j], s1 = bucket[o + j + 1];
            int s2 = bucket[o + j + 2], s3 = bucket[o + j + 3];
            v += x[(size_t)s0 * C + c];
            v += x[(size_t)s1 * C + c];
            v += x[(size_t)s2 * C + c];
            v += x[(size_t)s3 * C + c];
        }
        for (; j < d; j++) v += x[(size_t)bucket[o + j] * C + c];
        gsh[nl][c] = v;
    }
    __syncthreads();
    #pragma unroll
    for (int q = 0; q < 4; q++) {       // phi1: 16 nodes x 64
        int item = t + 256 * q;
        int node = item >> 6, j = item & 63;
        float h = b1[j];
        #pragma unroll
        for (int c = 0; c < C; c++) h = fmaf(gsh[node][c], w1s[c * DPE + j], h);
        h1sh[node][j] = fmaxf(h, 0.0f);
    }
    __syncthreads();
    #pragma unroll
    for (int q = 0; q < 4; q++) {       // phi2: 16 nodes x 64
        int item = t + 256 * q;
        int node = item >> 6, d = item & 63;
        float o2 = b2s[d];
        #pragma unroll
        for (int j = 0; j < DPE; j++) o2 = fmaf(h1sh[node][j], w2s[j * DPE + d], o2);
        out[((size_t)blockIdx.x * 16 + node) * DPE + d] = o2;
    }
}

extern "C" void kernel_launch(void* const* d_in, const int* in_sizes, int n_in,
                              void* d_out, int out_size, void* d_ws, size_t ws_size,
                              hipStream_t stream) {
    const float* Lap   = (const float*)d_in[0];
    const float* W     = (const float*)d_in[1];
    const float* lin_w = (const float*)d_in[2];
    const float* lin_b = (const float*)d_in[3];
    const float* gam   = (const float*)d_in[4];
    const float* bet   = (const float*)d_in[5];
    const float* w1    = (const float*)d_in[6];
    const float* b1    = (const float*)d_in[7];
    const float* w2    = (const float*)d_in[8];
    const float* b2    = (const float*)d_in[9];
    const int*   ei    = (const int*)d_in[10];

    char* wsb = (char*)d_ws;
    float* feat  = (float*)wsb;                              // 64 MB
    uint4* Sf    = (uint4*)(wsb + ((size_t)64 << 20));       // 32 MB
    uint4* Pf    = (uint4*)(wsb + ((size_t)96 << 20));       // 8 MB (2 buffers)
    float* stats = (float*)(wsb + ((size_t)104 << 20));      // small tail region
    unsigned* bar = (unsigned*)(stats + 256);                // 8 counters, 128B apart
    float* x     = stats + 2048;
    int*   cnt   = (int*)(x + (size_t)NV * C);
    int*   off   = cnt + NV;
    int*   cur   = off + NV;
    int*   bucket= cur + NV;                                 // NE ints
    float* out   = (float*)d_out;

    // allow 146 KB dynamic LDS (default cap is 64 KB); idempotent host-side call
    static bool attr_set = false;
    if (!attr_set) {
        hipFuncSetAttribute((const void*)gemm_chain,
                            hipFuncAttributeMaxDynamicSharedMemorySize, 149504);
        attr_set = true;
    }

    hipMemsetAsync(stats, 0, 8192, stream);                  // stats + bar
    hipMemsetAsync(cnt, 0, NV * sizeof(int), stream);
    prep_s<<<dim3(512), 256, 0, stream>>>(Lap, Sf);
    prep_w_plane<<<dim3(1024), 256, 0, stream>>>(W, feat);
    prep_w_frag<<<dim3(512), 256, 0, stream>>>(W, Pf);
    gemm_chain<<<dim3(256), 512, 149504, stream>>>(Sf, Pf, Pf + PFBUF, feat, bar);
    bn_stats<<<dim3(1024), 256, 0, stream>>>(feat, lin_w, lin_b, stats);
    bn_x<<<dim3(256), 256, 0, stream>>>(feat, lin_w, lin_b, gam, bet, stats, x);
    edge_hist<<<dim3(NE / 256), 256, 0, stream>>>(ei, cnt);
    edge_scan<<<dim3(1), 256, 0, stream>>>(cnt, off, cur);
    edge_fill<<<dim3(NE / 256), 256, 0, stream>>>(ei, cur, bucket);
    phi_fused<<<dim3(NV / 16), 256, 0, stream>>>(cnt, off, bucket, x, w1, b1, w2, b2, out);
}

// Round 18
// 293.099 us; speedup vs baseline: 1.6512x; 1.0702x over previous
//
#include <hip/hip_runtime.h>

#define B 8
#define N 1024
#define M 128
#define KF 16
#define C 16
#define DPE 64
#define NE 131072
#define NV (B*N)
#define NM (N*M)
#define BN_EPS 1e-5f

typedef short bf16x8 __attribute__((ext_vector_type(8)));
typedef float f32x4 __attribute__((ext_vector_type(4)));

__device__ inline unsigned short f2bf_rne(float f) {
    unsigned u = __float_as_uint(f);
    u += 0x7fffu + ((u >> 16) & 1u);
    return (unsigned short)(u >> 16);
}
__device__ inline float bf2f(unsigned short s) {
    return __uint_as_float((unsigned)s << 16);
}
__device__ inline void split_bf16(float v, unsigned short& hi, unsigned short& lo) {
    hi = f2bf_rne(v);
    float hf = __uint_as_float((unsigned)hi << 16);
    lo = f2bf_rne(v - hf);
}
union U4 { uint4 v; unsigned short s[8]; };
union U2 { uint2 v; unsigned short s[4]; };

// Sf frag-major (uint4 units): SF4(b,nsub,ks,hl,l) ; el = S[n=16nsub+(l&15)][k=32ks+8(l>>4)+j]
__device__ __host__ inline size_t SF4(int b, int nsub, int ks, int hl, int l) {
    return ((((size_t)b * 64 + nsub) * 32 + ks) * 2 + hl) * 64 + l;
}
// Pf frag-major (uint4 units) per buffer: PF4(b,msub,ks,hl,l)
__device__ __host__ inline size_t PF4(int b, int msub, int ks, int hl, int l) {
    return ((((size_t)b * 8 + msub) * 32 + ks) * 2 + hl) * 64 + l;
}
#define PFBUF ((size_t)B * 8 * 32 * 2 * 64)   // uint4 per Pf buffer (4MB)

// ---------- fused prep: S-frags | W plane0 | W-frags | edge histogram ----------
// Block ranges (each base is a multiple of 8 so blk&7 XCD pinning is kept):
// [0,512) prep_s; [512,1536) prep_w_plane(bf16); [1536,2048) prep_w_frag;
// [2048,2560) edge_hist.
__global__ __launch_bounds__(256) void prep_all(const float* __restrict__ Lap,
                                                const float* __restrict__ W,
                                                const int* __restrict__ ei,
                                                uint4* __restrict__ Sf,
                                                uint4* __restrict__ Pf,
                                                unsigned short* __restrict__ feat,
                                                int* __restrict__ cnt) {
    __shared__ float T[32][33];
    int blk = blockIdx.x;
    int t = threadIdx.x;
    if (blk < 512) {                          // ---- prep_s ----
        int b = blk & 7, nb = blk >> 3;
        int nl = t >> 4, kg = t & 15;
        int n = nb * 16 + nl;
        const float* row = Lap + ((size_t)b * N + n) * N;
        #pragma unroll
        for (int jj = 0; jj < 8; jj++) {
            int koct = kg + 16 * jj;
            int k0 = koct * 8;
            float4 f0 = *(const float4*)(row + k0);
            float4 f1 = *(const float4*)(row + k0 + 4);
            float e[8] = {f0.x, f0.y, f0.z, f0.w, f1.x, f1.y, f1.z, f1.w};
            U4 hi, lo;
            #pragma unroll
            for (int j = 0; j < 8; j++) split_bf16(e[j], hi.s[j], lo.s[j]);
            int ks = k0 >> 5;
            int lf = nl + 16 * (koct & 3);
            Sf[SF4(b, nb, ks, 0, lf)] = hi.v;
            Sf[SF4(b, nb, ks, 1, lf)] = lo.v;
        }
    } else if (blk < 1536) {                  // ---- prep_w_plane (bf16) ----
        int r = blk - 512;
        int b = r & 7;
        int tile = r >> 3;
        int nt = tile & 31, mt = tile >> 5;
        int n0 = nt * 32, m0 = mt * 32;
        {
            int nl = t >> 3, mq = t & 7;
            float4 v = *(const float4*)(W + ((size_t)b * N + n0 + nl) * M + m0 + mq * 4);
            T[nl][mq * 4 + 0] = v.x; T[nl][mq * 4 + 1] = v.y;
            T[nl][mq * 4 + 2] = v.z; T[nl][mq * 4 + 3] = v.w;
        }
        __syncthreads();
        {
            int ml = t >> 3, nq = t & 7;
            U2 o;
            o.s[0] = f2bf_rne(T[nq * 4 + 0][ml]);
            o.s[1] = f2bf_rne(T[nq * 4 + 1][ml]);
            o.s[2] = f2bf_rne(T[nq * 4 + 2][ml]);
            o.s[3] = f2bf_rne(T[nq * 4 + 3][ml]);
            unsigned short* plane = feat + (size_t)b * KF * NM;  // plane 0
            *(uint2*)(plane + (size_t)(m0 + ml) * N + n0 + nq * 4) = o.v;
        }
    } else if (blk < 2048) {                  // ---- prep_w_frag ----
        int r0 = blk - 1536;
        int b = r0 & 7;
        int r = (r0 >> 3) * 256 + t;
        int msub = r >> 11, ks = (r >> 6) & 31, l = r & 63;
        int m = 16 * msub + (l & 15);
        U4 hi, lo;
        #pragma unroll
        for (int j = 0; j < 8; j++) {
            int n = 32 * ks + 8 * (l >> 4) + j;
            float v = W[((size_t)b * N + n) * M + m];
            split_bf16(v, hi.s[j], lo.s[j]);
        }
        Pf[PF4(b, msub, ks, 0, l)] = hi.v;
        Pf[PF4(b, msub, ks, 1, l)] = lo.v;
    } else {                                  // ---- edge_hist ----
        int e = (blk - 2048) * 256 + t;
        bool is64 = (ei[1] == 0 && ei[3] == 0 && ei[5] == 0 && ei[7] == 0);
        int dst = is64 ? ei[2 * (NE + e)] : ei[NE + e];
        atomicAdd(&cnt[dst], 1);
    }
}

// ---------- persistent MFMA chain, Sf LDS-resident, bf16 feat planes ----------
// R17 structure (chain 151us): split-K 2-msub waves, 2-deep x4 prefetch ring,
// per-batch relaxed spin barrier + buffer_inv sc0. Delta R18: plane writes bf16.
__global__ __launch_bounds__(512) void gemm_chain(const uint4* __restrict__ Sf,
                                                  uint4* __restrict__ PfA,
                                                  uint4* __restrict__ PfB,
                                                  unsigned short* __restrict__ feat,
                                                  unsigned* bar) {
    extern __shared__ __align__(16) char smem[];
    uint4* ldsS = (uint4*)smem;               // 8192 uint4 = 128 KB
    float* Dl = (float*)(smem + 131072);      // 128 x 36 floats = 18.4 KB

    int b = blockIdx.x & 7, bx = blockIdx.x >> 3;   // XCD pinning
    int t = threadIdx.x;
    int w = t >> 6, lane = t & 63;
    int g = w >> 2, wq = w & 3;               // K-half, msub-pair
    size_t sbase = SF4(b, 2 * bx, 0, 0, 0);
    int n0 = 32 * bx;

    // one-time: Sf slice -> LDS (contiguous 8192 uint4)
    #pragma unroll
    for (int i = 0; i < 16; i++) ldsS[t + 512 * i] = Sf[sbase + t + 512 * i];
    __syncthreads();

    #pragma unroll 1
    for (int k = 0; k < KF - 1; k++) {
        const uint4* PfIn = (k & 1) ? PfB : PfA;
        uint4* PfOut      = (k & 1) ? PfA : PfB;
        const uint4* Pw0 = PfIn + (size_t)(b * 8 + 2 * wq) * 4096 + (size_t)(16 * g) * 128;
        const uint4* Pw1 = Pw0 + 4096;

        f32x4 acc[2][2] = {};                 // [mi][ni]
        uint4 ph[2][2], pl[2][2];             // [ring][mi]
        #pragma unroll
        for (int q = 0; q < 2; q++) {
            ph[q][0] = Pw0[(size_t)q * 128 + lane];
            pl[q][0] = Pw0[(size_t)q * 128 + 64 + lane];
            ph[q][1] = Pw1[(size_t)q * 128 + lane];
            pl[q][1] = Pw1[(size_t)q * 128 + 64 + lane];
        }
        #pragma unroll 2
        for (int ks = 0; ks < 16; ks++) {
            int kg = 16 * g + ks;
            uint4 a0h = ph[ks & 1][0], a0l = pl[ks & 1][0];
            uint4 a1h = ph[ks & 1][1], a1l = pl[ks & 1][1];
            if (ks < 14) {
                ph[ks & 1][0] = Pw0[(size_t)(ks + 2) * 128 + lane];
                pl[ks & 1][0] = Pw0[(size_t)(ks + 2) * 128 + 64 + lane];
                ph[ks & 1][1] = Pw1[(size_t)(ks + 2) * 128 + lane];
                pl[ks & 1][1] = Pw1[(size_t)(ks + 2) * 128 + 64 + lane];
            }
            bf16x8 b0h = __builtin_bit_cast(bf16x8, ldsS[kg * 128 + lane]);
            bf16x8 b0l = __builtin_bit_cast(bf16x8, ldsS[kg * 128 + 64 + lane]);
            bf16x8 b1h = __builtin_bit_cast(bf16x8, ldsS[4096 + kg * 128 + lane]);
            bf16x8 b1l = __builtin_bit_cast(bf16x8, ldsS[4096 + kg * 128 + 64 + lane]);
            bf16x8 A0h = __builtin_bit_cast(bf16x8, a0h);
            bf16x8 A0l = __builtin_bit_cast(bf16x8, a0l);
            bf16x8 A1h = __builtin_bit_cast(bf16x8, a1h);
            bf16x8 A1l = __builtin_bit_cast(bf16x8, a1l);
            acc[0][0] = __builtin_amdgcn_mfma_f32_16x16x32_bf16(A0h, b0h, acc[0][0], 0, 0, 0);
            acc[0][0] = __builtin_amdgcn_mfma_f32_16x16x32_bf16(A0h, b0l, acc[0][0], 0, 0, 0);
            acc[0][0] = __builtin_amdgcn_mfma_f32_16x16x32_bf16(A0l, b0h, acc[0][0], 0, 0, 0);
            acc[0][1] = __builtin_amdgcn_mfma_f32_16x16x32_bf16(A0h, b1h, acc[0][1], 0, 0, 0);
            acc[0][1] = __builtin_amdgcn_mfma_f32_16x16x32_bf16(A0h, b1l, acc[0][1], 0, 0, 0);
            acc[0][1] = __builtin_amdgcn_mfma_f32_16x16x32_bf16(A0l, b1h, acc[0][1], 0, 0, 0);
            acc[1][0] = __builtin_amdgcn_mfma_f32_16x16x32_bf16(A1h, b0h, acc[1][0], 0, 0, 0);
            acc[1][0] = __builtin_amdgcn_mfma_f32_16x16x32_bf16(A1h, b0l, acc[1][0], 0, 0, 0);
            acc[1][0] = __builtin_amdgcn_mfma_f32_16x16x32_bf16(A1l, b0h, acc[1][0], 0, 0, 0);
            acc[1][1] = __builtin_amdgcn_mfma_f32_16x16x32_bf16(A1h, b1h, acc[1][1], 0, 0, 0);
            acc[1][1] = __builtin_amdgcn_mfma_f32_16x16x32_bf16(A1h, b1l, acc[1][1], 0, 0, 0);
            acc[1][1] = __builtin_amdgcn_mfma_f32_16x16x32_bf16(A1l, b1h, acc[1][1], 0, 0, 0);
        }

        // ---- K-half reduction through Dl: g=1 writes, g=0 adds ----
        if (g == 1) {
            #pragma unroll
            for (int mi = 0; mi < 2; mi++)
                #pragma unroll
                for (int ni = 0; ni < 2; ni++)
                    #pragma unroll
                    for (int r = 0; r < 4; r++) {
                        int m = 32 * wq + 16 * mi + 4 * (lane >> 4) + r;
                        int c = 16 * ni + (lane & 15);
                        Dl[m * 36 + c] = acc[mi][ni][r];
                    }
        }
        __syncthreads();
        if (g == 0) {
            #pragma unroll
            for (int mi = 0; mi < 2; mi++)
                #pragma unroll
                for (int ni = 0; ni < 2; ni++)
                    #pragma unroll
                    for (int r = 0; r < 4; r++) {
                        int m = 32 * wq + 16 * mi + 4 * (lane >> 4) + r;
                        int c = 16 * ni + (lane & 15);
                        Dl[m * 36 + c] += acc[mi][ni][r];
                    }
        }
        __syncthreads();
        {   // bf16 plane write ([m][node]); 512 threads x 8 elems (one uint4)
            int m = t >> 2, c0 = (t & 3) * 8;
            U4 o;
            #pragma unroll
            for (int j = 0; j < 8; j++) o.s[j] = f2bf_rne(Dl[m * 36 + c0 + j]);
            unsigned short* plane = feat + ((size_t)b * KF + (k + 1)) * NM + (size_t)m * N + n0 + c0;
            *(uint4*)plane = o.v;
        }
        if (k < KF - 2) {
            {   // next-step A frags (hi/lo), ks = bx; msub = w
                int l = t & 63;
                int m = 16 * w + (l & 15);
                int ncol = 8 * (l >> 4);
                float4 v0 = *(const float4*)&Dl[m * 36 + ncol];
                float4 v1 = *(const float4*)&Dl[m * 36 + ncol + 4];
                float e[8] = {v0.x, v0.y, v0.z, v0.w, v1.x, v1.y, v1.z, v1.w};
                U4 hi, lo;
                #pragma unroll
                for (int j = 0; j < 8; j++) split_bf16(e[j], hi.s[j], lo.s[j]);
                PfOut[PF4(b, w, bx, 0, l)] = hi.v;
                PfOut[PF4(b, w, bx, 1, l)] = lo.v;
            }
            // ---- per-batch (same-XCD) barrier: no fences, no L2 flush ----
            __syncthreads();   // drains all waves' Pf stores to L2 (vmcnt(0))
            if (t == 0) {
                __hip_atomic_fetch_add(&bar[b * 32], 1u, __ATOMIC_RELAXED,
                                       __HIP_MEMORY_SCOPE_AGENT);
                unsigned target = 32u * (unsigned)(k + 1);
                while (__hip_atomic_load(&bar[b * 32], __ATOMIC_RELAXED,
                                         __HIP_MEMORY_SCOPE_AGENT) < target)
                    __builtin_amdgcn_s_sleep(1);
            }
            __syncthreads();
            // invalidate this CU's vector L1 so Pf reads come from (fresh) L2
            asm volatile("buffer_inv sc0\n\ts_waitcnt vmcnt(0)" ::: "memory");
        } else {
            __syncthreads();
        }
    }
}

// ---------- BN stats (XCD-aligned, bf16 feat) ----------
__global__ __launch_bounds__(256) void bn_stats(const unsigned short* __restrict__ feat,
                                                const float* __restrict__ lin_w,
                                                const float* __restrict__ lin_b,
                                                float* __restrict__ stats) {
    __shared__ float wls[KF * C];
    __shared__ float red[4][2][C];
    int t = threadIdx.x;
    wls[t] = lin_w[t];
    __syncthreads();
    int b = blockIdx.x & 7;
    int i = (blockIdx.x >> 3) * 256 + t;          // group of 4 elems, 32768/batch
    const uint2* fb = (const uint2*)(feat + (size_t)b * KF * NM);

    float4 hacc[C];
    #pragma unroll
    for (int c = 0; c < C; c++) {
        float bb = lin_b[c];
        hacc[c] = make_float4(bb, bb, bb, bb);
    }
    for (int kk = 0; kk < KF; kk++) {
        U2 u; u.v = fb[(size_t)kk * (NM / 4) + i];
        float p0 = bf2f(u.s[0]), p1 = bf2f(u.s[1]), p2 = bf2f(u.s[2]), p3 = bf2f(u.s[3]);
        #pragma unroll
        for (int c = 0; c < C; c++) {
            float wv = wls[kk * C + c];
            hacc[c].x = fmaf(p0, wv, hacc[c].x);
            hacc[c].y = fmaf(p1, wv, hacc[c].y);
            hacc[c].z = fmaf(p2, wv, hacc[c].z);
            hacc[c].w = fmaf(p3, wv, hacc[c].w);
        }
    }
    float s[C], ss[C];
    #pragma unroll
    for (int c = 0; c < C; c++) {
        float4 h = hacc[c];
        s[c] = h.x + h.y + h.z + h.w;
        ss[c] = h.x * h.x + h.y * h.y + h.z * h.z + h.w * h.w;
    }
    #pragma unroll
    for (int off = 32; off > 0; off >>= 1)
        #pragma unroll
        for (int c = 0; c < C; c++) {
            s[c] += __shfl_down(s[c], off);
            ss[c] += __shfl_down(ss[c], off);
        }
    if ((t & 63) == 0) {
        int wv = t >> 6;
        #pragma unroll
        for (int c = 0; c < C; c++) { red[wv][0][c] = s[c]; red[wv][1][c] = ss[c]; }
    }
    __syncthreads();
    if (t < 32) {
        int which = t >> 4, c = t & 15;
        float v = red[0][which][c] + red[1][which][c] + red[2][which][c] + red[3][which][c];
        atomicAdd(&stats[b * 32 + which * 16 + c], v);
    }
}

// ---------- BN apply + relu + mean over M -> x (bf16 feat) ----------
__global__ __launch_bounds__(256) void bn_x(const unsigned short* __restrict__ feat,
                                            const float* __restrict__ lin_w,
                                            const float* __restrict__ lin_b,
                                            const float* __restrict__ gam,
                                            const float* __restrict__ bet,
                                            const float* __restrict__ stats,
                                            float* __restrict__ x) {
    __shared__ float wls[KF * C];
    __shared__ float red[8][32 * 17];
    int t = threadIdx.x;
    wls[t] = lin_w[t];
    __syncthreads();
    int grp = blockIdx.x;
    int b = grp & 7, n0 = (grp >> 3) * 32;
    int nl = t & 31, mg = t >> 5;
    int n = n0 + nl;

    const float inv_nm = 1.0f / (float)NM;
    float sc[C], sh[C], bb[C];
    #pragma unroll
    for (int c = 0; c < C; c++) {
        float mean = stats[b * 32 + c] * inv_nm;
        float var = stats[b * 32 + 16 + c] * inv_nm - mean * mean;
        sc[c] = gam[c] * rsqrtf(var + BN_EPS);
        sh[c] = bet[c] - mean * sc[c];
        bb[c] = lin_b[c];
    }
    const unsigned short* fb = feat + (size_t)b * KF * NM + n;
    float y[C] = {};
    for (int m = mg * 16; m < mg * 16 + 16; m++) {
        float p[KF];
        #pragma unroll
        for (int kk = 0; kk < KF; kk++) p[kk] = bf2f(fb[(size_t)kk * NM + (size_t)m * N]);
        #pragma unroll
        for (int c = 0; c < C; c++) {
            float h = bb[c];
            #pragma unroll
            for (int kk = 0; kk < KF; kk++) h = fmaf(p[kk], wls[kk * C + c], h);
            y[c] += fmaxf(fmaf(h, sc[c], sh[c]), 0.0f);
        }
    }
    #pragma unroll
    for (int c = 0; c < C; c++) red[mg][nl * 17 + c] = y[c];
    __syncthreads();
    #pragma unroll
    for (int q = 0; q < 2; q++) {
        int slot = t + q * 256;
        int snl = slot >> 4, c = slot & 15;
        float v = 0.0f;
        #pragma unroll
        for (int m8 = 0; m8 < 8; m8++) v += red[m8][snl * 17 + c];
        v *= (1.0f / (float)M);
        x[((size_t)b * N + n0 + snl) * C + c] = v;
    }
}

// ---------- edge CSR scan + fill ----------
__global__ __launch_bounds__(256) void edge_scan(const int* __restrict__ cnt,
                                                 int* __restrict__ off, int* __restrict__ cur) {
    __shared__ int ss[256];
    int t = threadIdx.x;
    int base = t * 32;
    int local[32];
    int s = 0;
    #pragma unroll
    for (int i = 0; i < 32; i++) { local[i] = cnt[base + i]; s += local[i]; }
    ss[t] = s;
    __syncthreads();
    #pragma unroll
    for (int d = 1; d < 256; d <<= 1) {
        int v = (t >= d) ? ss[t - d] : 0;
        __syncthreads();
        ss[t] += v;
        __syncthreads();
    }
    int excl = ss[t] - s;
    #pragma unroll
    for (int i = 0; i < 32; i++) { off[base + i] = excl; cur[base + i] = excl; excl += local[i]; }
}

__global__ __launch_bounds__(256) void edge_fill(const int* __restrict__ ei,
                                                 int* __restrict__ cur, int* __restrict__ bucket) {
    int e = blockIdx.x * 256 + threadIdx.x;
    bool is64 = (ei[1] == 0 && ei[3] == 0 && ei[5] == 0 && ei[7] == 0);
    int src, dst;
    if (is64) { src = ei[2 * e]; dst = ei[2 * (NE + e)]; }
    else      { src = ei[e];     dst = ei[NE + e]; }
    int pos = atomicAdd(&cur[dst], 1);
    bucket[pos] = src;
}

// ---------- fused gather + phi1 + phi2 ----------
__global__ __launch_bounds__(256) void phi_fused(const int* __restrict__ cnt,
                                                 const int* __restrict__ off,
                                                 const int* __restrict__ bucket,
                                                 const float* __restrict__ x,
                                                 const float* __restrict__ w1,
                                                 const float* __restrict__ b1,
                                                 const float* __restrict__ w2,
                                                 const float* __restrict__ b2,
                                                 float* __restrict__ out) {
    __shared__ float w1s[C * DPE];
    __shared__ float w2s[DPE * DPE];
    __shared__ float b2s[DPE];
    __shared__ float gsh[16][17];
    __shared__ float h1sh[16][DPE];
    int t = threadIdx.x;
    #pragma unroll
    for (int q = 0; q < 4; q++) w1s[t + q * 256] = w1[t + q * 256];
    #pragma unroll
    for (int q = 0; q < 16; q++) w2s[t + q * 256] = w2[t + q * 256];
    if (t < DPE) b2s[t] = b2[t];

    {   // gather: node nl, channel c
        int nl = t >> 4, c = t & 15;
        int n = blockIdx.x * 16 + nl;
        int o = off[n], d = cnt[n];
        float v = x[(size_t)n * C + c];
        int j = 0;
        for (; j + 4 <= d; j += 4) {
            int s0 = bucket[o + j], s1 = bucket[o + j + 1];
            int s2 = bucket[o + j + 2], s3 = bucket[o + j + 3];
            v += x[(size_t)s0 * C + c];
            v += x[(size_t)s1 * C + c];
            v += x[(size_t)s2 * C + c];
            v += x[(size_t)s3 * C + c];
        }
        for (; j < d; j++) v += x[(size_t)bucket[o + j] * C + c];
        gsh[nl][c] = v;
    }
    __syncthreads();
    #pragma unroll
    for (int q = 0; q < 4; q++) {       // phi1: 16 nodes x 64
        int item = t + 256 * q;
        int node = item >> 6, j = item & 63;
        float h = b1[j];
        #pragma unroll
        for (int c = 0; c < C; c++) h = fmaf(gsh[node][c], w1s[c * DPE + j], h);
        h1sh[node][j] = fmaxf(h, 0.0f);
    }
    __syncthreads();
    #pragma unroll
    for (int q = 0; q < 4; q++) {       // phi2: 16 nodes x 64
        int item = t + 256 * q;
        int node = item >> 6, d = item & 63;
        float o2 = b2s[d];
        #pragma unroll
        for (int j = 0; j < DPE; j++) o2 = fmaf(h1sh[node][j], w2s[j * DPE + d], o2);
        out[((size_t)blockIdx.x * 16 + node) * DPE + d] = o2;
    }
}

extern "C" void kernel_launch(void* const* d_in, const int* in_sizes, int n_in,
                              void* d_out, int out_size, void* d_ws, size_t ws_size,
                              hipStream_t stream) {
    const float* Lap   = (const float*)d_in[0];
    const float* W     = (const float*)d_in[1];
    const float* lin_w = (const float*)d_in[2];
    const float* lin_b = (const float*)d_in[3];
    const float* gam   = (const float*)d_in[4];
    const float* bet   = (const float*)d_in[5];
    const float* w1    = (const float*)d_in[6];
    const float* b1    = (const float*)d_in[7];
    const float* w2    = (const float*)d_in[8];
    const float* b2    = (const float*)d_in[9];
    const int*   ei    = (const int*)d_in[10];

    char* wsb = (char*)d_ws;
    unsigned short* feat = (unsigned short*)wsb;             // 32 MB (bf16)
    uint4* Sf    = (uint4*)(wsb + ((size_t)32 << 20));       // 32 MB
    uint4* Pf    = (uint4*)(wsb + ((size_t)64 << 20));       // 8 MB (2 buffers)
    float* stats = (float*)(wsb + ((size_t)72 << 20));       // small tail region
    unsigned* bar = (unsigned*)(stats + 256);                // 8 counters, 128B apart
    float* x     = stats + 2048;
    int*   cnt   = (int*)(x + (size_t)NV * C);
    int*   off   = cnt + NV;
    int*   cur   = off + NV;
    int*   bucket= cur + NV;                                 // NE ints
    float* out   = (float*)d_out;

    // allow 146 KB dynamic LDS (default cap is 64 KB); idempotent host-side call
    static bool attr_set = false;
    if (!attr_set) {
        hipFuncSetAttribute((const void*)gemm_chain,
                            hipFuncAttributeMaxDynamicSharedMemorySize, 149504);
        attr_set = true;
    }

    hipMemsetAsync(stats, 0, 8192, stream);                  // stats + bar
    hipMemsetAsync(cnt, 0, NV * sizeof(int), stream);
    prep_all<<<dim3(2560), 256, 0, stream>>>(Lap, W, ei, Sf, Pf, feat, cnt);
    gemm_chain<<<dim3(256), 512, 149504, stream>>>(Sf, Pf, Pf + PFBUF, feat, bar);
    bn_stats<<<dim3(1024), 256, 0, stream>>>(feat, lin_w, lin_b, stats);
    bn_x<<<dim3(256), 256, 0, stream>>>(feat, lin_w, lin_b, gam, bet, stats, x);
    edge_scan<<<dim3(1), 256, 0, stream>>>(cnt, off, cur);
    edge_fill<<<dim3(NE / 256), 256, 0, stream>>>(ei, cur, bucket);
    phi_fused<<<dim3(NV / 16), 256, 0, stream>>>(cnt, off, bucket, x, w1, b1, w2, b2, out);
}